// Round 2
// baseline (2775.180 us; speedup 1.0000x reference)
//
#include <hip/hip_runtime.h>
#include <hip/hip_bf16.h>

#define DD 1024
#define NB 4
#define TT 1024
#define NH 16
#define NS 4
#define LKV 1028   // NS + TT

__device__ __forceinline__ float warp_sum(float v) {
#pragma unroll
    for (int o = 32; o > 0; o >>= 1) v += __shfl_xor(v, o);
    return v;
}

// ---------------- positional encoding table ----------------
__global__ __launch_bounds__(256) void pe_kernel(float* __restrict__ pe) {
    int t = blockIdx.x;
    int tid = threadIdx.x;
#pragma unroll
    for (int i = 0; i < 2; ++i) {
        int j = i * 256 + tid;                       // 0..511
        float ang = (float)t * exp2f(-(float)j * (1.0f / 256.0f)); // t * 4^(-j/512)
        pe[(size_t)t * DD + j]        = sinf(ang);
        pe[(size_t)t * DD + 512 + j]  = cosf(ang);
    }
}

// ---------------- LayerNorm (one block per row) ----------------
__global__ __launch_bounds__(256) void ln_kernel(
    const float* __restrict__ in, float* __restrict__ out,
    const float* __restrict__ g, const float* __restrict__ b,
    int row0, int rstride)
{
    int r = blockIdx.x;
    int tid = threadIdx.x;
    size_t base = (size_t)(row0 + (size_t)r * rstride) * DD;
    float v[4];
    float s1 = 0.f, s2 = 0.f;
#pragma unroll
    for (int i = 0; i < 4; ++i) {
        v[i] = in[base + i * 256 + tid];
        s1 += v[i]; s2 += v[i] * v[i];
    }
    s1 = warp_sum(s1); s2 = warp_sum(s2);
    __shared__ float a1[4], a2[4];
    int w = tid >> 6;
    if ((tid & 63) == 0) { a1[w] = s1; a2[w] = s2; }
    __syncthreads();
    s1 = a1[0] + a1[1] + a1[2] + a1[3];
    s2 = a2[0] + a2[1] + a2[2] + a2[3];
    float mu  = s1 * (1.0f / DD);
    float var = s2 * (1.0f / DD) - mu * mu;
    var = var < 0.f ? 0.f : var;
    float rs = rsqrtf(var + 1e-5f);
#pragma unroll
    for (int i = 0; i < 4; ++i) {
        int c = i * 256 + tid;
        out[(size_t)r * DD + c] = (v[i] - mu) * rs * g[c] + b[c];
    }
}

// ---------------- GEMM: C[m][n] = sum_k A[m][k]*W[n][k] + bias[n] ----------------
// epilogue: optional gelu, optional residual res[m][n], optional pe[(m%rpb)][n]
// out row remap: orow = (m/rpb)*obs + oro + (m%rpb)
__global__ __launch_bounds__(256) void gemm_kernel(
    const float* __restrict__ A, const float* __restrict__ W,
    const float* __restrict__ bias, float* __restrict__ out,
    int M, int rpb, int obs, int oro,
    const float* __restrict__ pe, const float* __restrict__ res, int gelu)
{
    __shared__ float As[64][17];
    __shared__ float Bs[64][17];
    int tid = threadIdx.x;
    int tx = tid & 15, ty = tid >> 4;
    int m0 = blockIdx.y * 64;
    int n0 = blockIdx.x * 64;
    float acc[4][4] = {};
    for (int k0 = 0; k0 < DD; k0 += 16) {
#pragma unroll
        for (int r = 0; r < 4; ++r) {
            int row = ty + r * 16;
            int m = m0 + row;
            As[row][tx] = (m < M) ? A[(size_t)m * DD + k0 + tx] : 0.f;
            Bs[row][tx] = W[(size_t)(n0 + row) * DD + k0 + tx];
        }
        __syncthreads();
#pragma unroll
        for (int k = 0; k < 16; ++k) {
            float a[4], b[4];
#pragma unroll
            for (int i = 0; i < 4; ++i) a[i] = As[ty * 4 + i][k];
#pragma unroll
            for (int j = 0; j < 4; ++j) b[j] = Bs[tx * 4 + j][k];
#pragma unroll
            for (int i = 0; i < 4; ++i)
#pragma unroll
                for (int j = 0; j < 4; ++j)
                    acc[i][j] += a[i] * b[j];
        }
        __syncthreads();
    }
#pragma unroll
    for (int i = 0; i < 4; ++i) {
        int m = m0 + ty * 4 + i;
        if (m >= M) continue;
        int orow = (m / rpb) * obs + oro + (m % rpb);
        int prow = m % rpb;
#pragma unroll
        for (int j = 0; j < 4; ++j) {
            int n = n0 + tx * 4 + j;
            float v = acc[i][j] + bias[n];
            if (gelu) v = 0.5f * v * (1.0f + erff(v * 0.70710678118654752f));
            if (res)  v += res[(size_t)m * DD + n];
            if (pe)   v += pe[(size_t)prow * DD + n];
            out[(size_t)orow * DD + n] = v;
        }
    }
}

// ---------------- attention: one block per (b,h); wave w handles query w ----------------
__global__ __launch_bounds__(256) void attn_kernel(
    const float* __restrict__ qh, const float* __restrict__ kh,
    const float* __restrict__ vh, float* __restrict__ out, int Lq)
{
    __shared__ float sc[4][LKV];
    __shared__ float qs[4][64];
    int tid = threadIdx.x;
    int lane = tid & 63;
    int w = tid >> 6;
    int bh = blockIdx.x;
    int b = bh >> 4;       // / NH
    int h = bh & 15;
    int qi = w;
    bool act = qi < Lq;
    if (act) qs[w][lane] = qh[(size_t)(b * Lq + qi) * DD + h * 64 + lane];
    __syncthreads();
    if (act) {
        // scores
        for (int kb = 0; kb < LKV; kb += 64) {
            int key = kb + lane;
            if (key < LKV) {
                const float* kr = kh + (size_t)(b * LKV + key) * DD + h * 64;
                float s = 0.f;
#pragma unroll
                for (int d = 0; d < 64; ++d) s += qs[w][d] * kr[d];
                sc[w][key] = s * 0.125f;   // / sqrt(64)
            }
        }
        // max
        float mx = -1e30f;
        for (int key = lane; key < LKV; key += 64) mx = fmaxf(mx, sc[w][key]);
#pragma unroll
        for (int o = 32; o > 0; o >>= 1) mx = fmaxf(mx, __shfl_xor(mx, o));
        // exp + sum
        float ssum = 0.f;
        for (int key = lane; key < LKV; key += 64) {
            float e = expf(sc[w][key] - mx);
            sc[w][key] = e;
            ssum += e;
        }
        ssum = warp_sum(ssum);
        float inv = 1.f / ssum;
        // PV: lane owns dim d = lane
        float acc = 0.f;
        for (int key = 0; key < LKV; ++key)
            acc += sc[w][key] * vh[(size_t)(b * LKV + key) * DD + h * 64 + lane];
        out[(size_t)(b * Lq + qi) * DD + h * 64 + lane] = acc * inv;
    }
}

// ---------------- small copies ----------------
__global__ __launch_bounds__(256) void copy_state_kernel(
    const float* __restrict__ sf, float* __restrict__ cat)
{
    int r = blockIdx.x;          // b*4+s
    int b = r >> 2, s = r & 3;
    int tid = threadIdx.x;
#pragma unroll
    for (int i = 0; i < 4; ++i)
        cat[(size_t)(b * LKV + s) * DD + i * 256 + tid] = sf[(size_t)r * DD + i * 256 + tid];
}

__global__ __launch_bounds__(256) void copy_lolast_kernel(
    const float* __restrict__ cat, float* __restrict__ dst)
{
    int b = blockIdx.x;
    int tid = threadIdx.x;
#pragma unroll
    for (int i = 0; i < 4; ++i)
        dst[(size_t)b * DD + i * 256 + tid] =
            cat[(size_t)(b * LKV + (TT - 1)) * DD + i * 256 + tid];
}

// ---------------- slot logits ----------------
__global__ __launch_bounds__(256) void logits_kernel(
    const float* __restrict__ ln, const float* __restrict__ ctx, float* __restrict__ out)
{
    int r = blockIdx.x;
    int tid = threadIdx.x;
    float s = 0.f;
    for (int i = tid; i < DD; i += 256) s += ln[(size_t)r * DD + i] * ctx[i];
    s = warp_sum(s);
    __shared__ float a[4];
    if ((tid & 63) == 0) a[tid >> 6] = s;
    __syncthreads();
    if (tid == 0) out[r] = a[0] + a[1] + a[2] + a[3];
}

// ---------------- top-2 gate + state update (f32 outputs) ----------------
__global__ __launch_bounds__(256) void gate_kernel(
    const float* __restrict__ logits, const float* __restrict__ state_old,
    const float* __restrict__ lat2, float* __restrict__ cat_o,
    float* __restrict__ dout)
{
    int b = blockIdx.x;
    int tid = threadIdx.x;
    __shared__ float alpha[NS];
    if (tid == 0) {
        float l[NS];
        for (int s = 0; s < NS; ++s) l[s] = logits[b * NS + s];
        int i0 = 0;
        for (int s = 1; s < NS; ++s) if (l[s] > l[i0]) i0 = s;   // strict > : lowest idx on tie
        int i1 = (i0 == 0) ? 1 : 0;
        for (int s = 0; s < NS; ++s) if (s != i0 && l[s] > l[i1]) i1 = s;
        float mx = fmaxf(l[i0], l[i1]);
        float e0 = expf(l[i0] - mx), e1 = expf(l[i1] - mx);
        float inv = 1.f / (e0 + e1);
        for (int s = 0; s < NS; ++s) alpha[s] = 0.f;
        alpha[i0] = e0 * inv;
        alpha[i1] += e1 * inv;
        dout[4096 + b * 2 + 0] = (float)i0;
        dout[4096 + b * 2 + 1] = (float)i1;
    }
    __syncthreads();
    for (int idx = tid; idx < NS * DD; idx += 256) {
        int s = idx >> 10;
        int d = idx & 1023;
        float so = state_old[(size_t)b * NS * DD + idx];
        float lt = lat2[(size_t)b * NS * DD + idx];
        float ns = 0.6f * so + 0.4f * alpha[s] * tanhf(lt);
        cat_o[(size_t)(b * LKV + TT + s) * DD + d] = ns;      // for out-branch concat
        dout[4104 + b * NS * DD + idx] = ns;                   // output 2 (f32)
    }
}

extern "C" void kernel_launch(void* const* d_in, const int* in_sizes, int n_in,
                              void* d_out, int out_size, void* d_ws, size_t ws_size,
                              hipStream_t stream)
{
    const float* x        = (const float*)d_in[0];
    const float* state0   = (const float*)d_in[1];
    const float* se_W     = (const float*)d_in[2];
    const float* se_b     = (const float*)d_in[3];
    const float* s_Wq     = (const float*)d_in[4];
    const float* s_bq     = (const float*)d_in[5];
    const float* s_Wk     = (const float*)d_in[6];
    const float* s_bk     = (const float*)d_in[7];
    const float* s_Wv     = (const float*)d_in[8];
    const float* s_bv     = (const float*)d_in[9];
    const float* s_Wo     = (const float*)d_in[10];
    const float* s_bo     = (const float*)d_in[11];
    const float* s_lnq_g  = (const float*)d_in[12];
    const float* s_lnq_b  = (const float*)d_in[13];
    const float* s_lnkv_g = (const float*)d_in[14];
    const float* s_lnkv_b = (const float*)d_in[15];
    const float* s_fc1_W  = (const float*)d_in[16];
    const float* s_fc1_b  = (const float*)d_in[17];
    const float* s_fc2_W  = (const float*)d_in[18];
    const float* s_fc2_b  = (const float*)d_in[19];
    const float* s_lnffn_g= (const float*)d_in[20];
    const float* s_lnffn_b= (const float*)d_in[21];
    const float* s_lnslot_g=(const float*)d_in[22];
    const float* s_lnslot_b=(const float*)d_in[23];
    const float* slot_ctx = (const float*)d_in[24];
    const float* oe_W     = (const float*)d_in[25];
    const float* oe_b     = (const float*)d_in[26];
    const float* o_Wq     = (const float*)d_in[27];
    const float* o_bq     = (const float*)d_in[28];
    const float* o_Wk     = (const float*)d_in[29];
    const float* o_bk     = (const float*)d_in[30];
    const float* o_Wv     = (const float*)d_in[31];
    const float* o_bv     = (const float*)d_in[32];
    const float* o_Wo     = (const float*)d_in[33];
    const float* o_bo     = (const float*)d_in[34];
    const float* o_lnq_g  = (const float*)d_in[35];
    const float* o_lnq_b  = (const float*)d_in[36];
    const float* o_lnkv_g = (const float*)d_in[37];
    const float* o_lnkv_b = (const float*)d_in[38];
    const float* o_fc1_W  = (const float*)d_in[39];
    const float* o_fc1_b  = (const float*)d_in[40];
    const float* o_fc2_W  = (const float*)d_in[41];
    const float* o_fc2_b  = (const float*)d_in[42];
    const float* o_lnffn_g= (const float*)d_in[43];
    const float* o_lnffn_b= (const float*)d_in[44];
    const float* op_W     = (const float*)d_in[45];
    const float* op_b     = (const float*)d_in[46];

    float* ws  = (float*)d_ws;
    float* pe  = ws;                       // 1,048,576
    float* cat = ws + 1048576;             // 4,210,688  (concat buffer, reused both branches)
    float* lnb = cat + 4210688;            // 4,210,688  (LN of concat, reused)
    float* kh  = lnb + 4210688;            // 4,210,688  (K heads, reused)
    float* vh  = kh + 4210688;             // 4,210,688  (V heads, reused)
    float* sm  = vh + 4210688;             // small buffers
    float* q_s    = sm;
    float* qh_s   = sm + 16384;
    float* attn_s = sm + 32768;
    float* lat1   = sm + 49152;
    float* hffn   = sm + 65536;
    float* g1     = sm + 81920;
    float* lat2   = sm + 98304;
    float* lnslot = sm + 114688;
    float* logitsb= sm + 131072;           // 16 (+pad)
    float* q2     = sm + 131136;
    float* q2h    = q2 + 4096;
    float* attn2  = q2h + 4096;
    float* lo_last= attn2 + 4096;
    float* lo1    = lo_last + 4096;
    float* h2     = lo1 + 4096;
    float* g2     = h2 + 4096;
    float* lo2    = g2 + 4096;
    float* out = (float*)d_out;

    dim3 blk(256);

    // ---- shared precompute ----
    pe_kernel<<<TT, blk, 0, stream>>>(pe);

    // ---- state branch ----
    copy_state_kernel<<<16, blk, 0, stream>>>(state0, cat);              // cat rows b*1028+s
    gemm_kernel<<<dim3(16, 64), blk, 0, stream>>>(x, se_W, se_b, cat,    // lx -> cat rows b*1028+4+t
        4096, 1024, LKV, NS, pe, nullptr, 0);
    ln_kernel<<<16, blk, 0, stream>>>(state0, q_s, s_lnq_g, s_lnq_b, 0, 1);
    ln_kernel<<<4112, blk, 0, stream>>>(cat, lnb, s_lnkv_g, s_lnkv_b, 0, 1);
    gemm_kernel<<<dim3(16, 1), blk, 0, stream>>>(q_s, s_Wq, s_bq, qh_s,
        16, 16, 0, 0, nullptr, nullptr, 0);
    gemm_kernel<<<dim3(16, 65), blk, 0, stream>>>(lnb, s_Wk, s_bk, kh,
        4112, 4112, 0, 0, nullptr, nullptr, 0);
    gemm_kernel<<<dim3(16, 65), blk, 0, stream>>>(lnb, s_Wv, s_bv, vh,
        4112, 4112, 0, 0, nullptr, nullptr, 0);
    attn_kernel<<<64, blk, 0, stream>>>(qh_s, kh, vh, attn_s, 4);
    gemm_kernel<<<dim3(16, 1), blk, 0, stream>>>(attn_s, s_Wo, s_bo, lat1,
        16, 16, 0, 0, nullptr, state0, 0);                               // + residual(state_old)
    ln_kernel<<<16, blk, 0, stream>>>(lat1, hffn, s_lnffn_g, s_lnffn_b, 0, 1);
    gemm_kernel<<<dim3(16, 1), blk, 0, stream>>>(hffn, s_fc1_W, s_fc1_b, g1,
        16, 16, 0, 0, nullptr, nullptr, 1);                              // gelu
    gemm_kernel<<<dim3(16, 1), blk, 0, stream>>>(g1, s_fc2_W, s_fc2_b, lat2,
        16, 16, 0, 0, nullptr, lat1, 0);                                 // + residual(lat1)
    ln_kernel<<<16, blk, 0, stream>>>(lat2, lnslot, s_lnslot_g, s_lnslot_b, 0, 1);
    logits_kernel<<<16, blk, 0, stream>>>(lnslot, slot_ctx, logitsb);
    gate_kernel<<<NB, blk, 0, stream>>>(logitsb, state0, lat2, cat, out); // writes cat rows b*1028+1024+s, out idx+state

    // ---- out branch ----
    gemm_kernel<<<dim3(16, 64), blk, 0, stream>>>(x, oe_W, oe_b, cat,     // lo -> cat rows b*1028+t
        4096, 1024, LKV, 0, pe, nullptr, 0);
    ln_kernel<<<NB, blk, 0, stream>>>(cat, q2, o_lnq_g, o_lnq_b, TT - 1, LKV); // LN(lo[:, -1])
    ln_kernel<<<4112, blk, 0, stream>>>(cat, lnb, o_lnkv_g, o_lnkv_b, 0, 1);
    gemm_kernel<<<dim3(16, 1), blk, 0, stream>>>(q2, o_Wq, o_bq, q2h,
        4, 4, 0, 0, nullptr, nullptr, 0);
    gemm_kernel<<<dim3(16, 65), blk, 0, stream>>>(lnb, o_Wk, o_bk, kh,
        4112, 4112, 0, 0, nullptr, nullptr, 0);
    gemm_kernel<<<dim3(16, 65), blk, 0, stream>>>(lnb, o_Wv, o_bv, vh,
        4112, 4112, 0, 0, nullptr, nullptr, 0);
    attn_kernel<<<64, blk, 0, stream>>>(q2h, kh, vh, attn2, 1);
    copy_lolast_kernel<<<NB, blk, 0, stream>>>(cat, lo_last);
    gemm_kernel<<<dim3(16, 1), blk, 0, stream>>>(attn2, o_Wo, o_bo, lo1,
        4, 4, 0, 0, nullptr, lo_last, 0);                                 // + residual(lo_last)
    ln_kernel<<<NB, blk, 0, stream>>>(lo1, h2, o_lnffn_g, o_lnffn_b, 0, 1);
    gemm_kernel<<<dim3(16, 1), blk, 0, stream>>>(h2, o_fc1_W, o_fc1_b, g2,
        4, 4, 0, 0, nullptr, nullptr, 1);                                 // gelu
    gemm_kernel<<<dim3(16, 1), blk, 0, stream>>>(g2, o_fc2_W, o_fc2_b, lo2,
        4, 4, 0, 0, nullptr, lo1, 0);                                     // + residual(lo1)
    gemm_kernel<<<dim3(16, 1), blk, 0, stream>>>(lo2, op_W, op_b, out,    // y -> dout[0..4095]
        4, 4, 0, 0, nullptr, nullptr, 0);
}

// Round 3
// 1451.835 us; speedup vs baseline: 1.9115x; 1.9115x over previous
//
#include <hip/hip_runtime.h>
#include <hip/hip_bf16.h>

#define DD 1024
#define NB 4
#define TT 1024
#define NH 16
#define NS 4
#define LKV 1028   // NS + TT
#define MPAD 4224  // 33*128

typedef __hip_bfloat16 bf16;
typedef __attribute__((ext_vector_type(8))) short short8;
typedef __attribute__((ext_vector_type(4))) float f32x4;

#define GLD16(gp, lp) __builtin_amdgcn_global_load_lds( \
    (const __attribute__((address_space(1))) unsigned int*)(const void*)(gp), \
    (__attribute__((address_space(3))) unsigned int*)(void*)(lp), 16, 0, 0)

__device__ __forceinline__ float warp_sum(float v) {
#pragma unroll
    for (int o = 32; o > 0; o >>= 1) v += __shfl_xor(v, o);
    return v;
}

__device__ __forceinline__ float b2f(unsigned short u) {
    union { unsigned int i; float f; } x; x.i = ((unsigned)u) << 16; return x.f;
}

// ---------------- f32 -> bf16 conversion (4 elems/thread) ----------------
__global__ __launch_bounds__(256) void cvt_kernel(
    const float* __restrict__ in, bf16* __restrict__ out)
{
    int i = (blockIdx.x * 256 + threadIdx.x) * 4;
    float4 v = *(const float4*)(in + i);
    out[i + 0] = __float2bfloat16(v.x);
    out[i + 1] = __float2bfloat16(v.y);
    out[i + 2] = __float2bfloat16(v.z);
    out[i + 3] = __float2bfloat16(v.w);
}

// ---------------- positional encoding table ----------------
__global__ __launch_bounds__(256) void pe_kernel(float* __restrict__ pe) {
    int t = blockIdx.x;
    int tid = threadIdx.x;
#pragma unroll
    for (int i = 0; i < 2; ++i) {
        int j = i * 256 + tid;                       // 0..511
        float ang = (float)t * exp2f(-(float)j * (1.0f / 256.0f)); // t * 4^(-j/512)
        pe[(size_t)t * DD + j]        = sinf(ang);
        pe[(size_t)t * DD + 512 + j]  = cosf(ang);
    }
}

// ---------------- LayerNorm f32 out ----------------
__global__ __launch_bounds__(256) void ln_kernel(
    const float* __restrict__ in, float* __restrict__ out,
    const float* __restrict__ g, const float* __restrict__ b,
    int row0, int rstride)
{
    int r = blockIdx.x;
    int tid = threadIdx.x;
    size_t base = (size_t)(row0 + (size_t)r * rstride) * DD;
    float v[4];
    float s1 = 0.f, s2 = 0.f;
#pragma unroll
    for (int i = 0; i < 4; ++i) {
        v[i] = in[base + i * 256 + tid];
        s1 += v[i]; s2 += v[i] * v[i];
    }
    s1 = warp_sum(s1); s2 = warp_sum(s2);
    __shared__ float a1[4], a2[4];
    int w = tid >> 6;
    if ((tid & 63) == 0) { a1[w] = s1; a2[w] = s2; }
    __syncthreads();
    s1 = a1[0] + a1[1] + a1[2] + a1[3];
    s2 = a2[0] + a2[1] + a2[2] + a2[3];
    float mu  = s1 * (1.0f / DD);
    float var = s2 * (1.0f / DD) - mu * mu;
    var = var < 0.f ? 0.f : var;
    float rs = rsqrtf(var + 1e-5f);
#pragma unroll
    for (int i = 0; i < 4; ++i) {
        int c = i * 256 + tid;
        out[(size_t)r * DD + c] = (v[i] - mu) * rs * g[c] + b[c];
    }
}

// ---------------- LayerNorm bf16 out ----------------
__global__ __launch_bounds__(256) void ln_bf16_kernel(
    const float* __restrict__ in, bf16* __restrict__ out,
    const float* __restrict__ g, const float* __restrict__ b)
{
    int r = blockIdx.x;
    int tid = threadIdx.x;
    size_t base = (size_t)r * DD;
    float v[4];
    float s1 = 0.f, s2 = 0.f;
#pragma unroll
    for (int i = 0; i < 4; ++i) {
        v[i] = in[base + i * 256 + tid];
        s1 += v[i]; s2 += v[i] * v[i];
    }
    s1 = warp_sum(s1); s2 = warp_sum(s2);
    __shared__ float a1[4], a2[4];
    int w = tid >> 6;
    if ((tid & 63) == 0) { a1[w] = s1; a2[w] = s2; }
    __syncthreads();
    s1 = a1[0] + a1[1] + a1[2] + a1[3];
    s2 = a2[0] + a2[1] + a2[2] + a2[3];
    float mu  = s1 * (1.0f / DD);
    float var = s2 * (1.0f / DD) - mu * mu;
    var = var < 0.f ? 0.f : var;
    float rs = rsqrtf(var + 1e-5f);
#pragma unroll
    for (int i = 0; i < 4; ++i) {
        int c = i * 256 + tid;
        out[base + c] = __float2bfloat16((v[i] - mu) * rs * g[c] + b[c]);
    }
}

// ---------------- bf16 MFMA GEMM: C[m][n] = sum_k A[m][k]*W[n][k] + bias[n] ----
// 128x128 tile, BK=32, 4 waves (2x2), 16x16x32 MFMA, global_load_lds staging.
// outf != null: f32 out with row remap (rpb=1024) + pe add.
// outf == null: bf16 out at [row][n], predicated row < M.
__global__ __launch_bounds__(256) void mfma_gemm_kernel(
    const bf16* __restrict__ A, const bf16* __restrict__ W,
    const float* __restrict__ bias,
    float* __restrict__ outf, bf16* __restrict__ outb,
    int M, int obs, int oro, const float* __restrict__ pe)
{
    __shared__ bf16 As[128 * 32];
    __shared__ bf16 Ws[128 * 32];
    int tid  = threadIdx.x;
    int lane = tid & 63;
    int wave = tid >> 6;
    int m0 = blockIdx.y * 128;
    int n0 = blockIdx.x * 128;
    int wm = (wave >> 1) << 6;     // 0 / 64
    int wn = (wave & 1) << 6;      // 0 / 64

    f32x4 acc[4][4] = {};

    // staging geometry: byte off = issue*4096 + wave*1024 + lane*16
    int soff  = wave * 1024 + lane * 16;   // issue-0 byte offset
    int srow  = soff >> 6;                 // row in tile (64B rows)
    int scol  = (soff & 63) >> 1;          // bf16 column
    char* lA0 = (char*)As + wave * 1024;
    char* lA1 = (char*)As + 4096 + wave * 1024;
    char* lW0 = (char*)Ws + wave * 1024;
    char* lW1 = (char*)Ws + 4096 + wave * 1024;

    int fRow = lane & 15;
    int kOff = (lane >> 4) << 3;           // 0,8,16,24

    for (int k0 = 0; k0 < DD; k0 += 32) {
        GLD16(A + (size_t)(m0 + srow) * DD + k0 + scol,      lA0);
        GLD16(A + (size_t)(m0 + 64 + srow) * DD + k0 + scol, lA1);
        GLD16(W + (size_t)(n0 + srow) * DD + k0 + scol,      lW0);
        GLD16(W + (size_t)(n0 + 64 + srow) * DD + k0 + scol, lW1);
        __syncthreads();
        short8 a[4], b[4];
#pragma unroll
        for (int mi = 0; mi < 4; ++mi)
            a[mi] = *(const short8*)(As + (wm + mi * 16 + fRow) * 32 + kOff);
#pragma unroll
        for (int ni = 0; ni < 4; ++ni)
            b[ni] = *(const short8*)(Ws + (wn + ni * 16 + fRow) * 32 + kOff);
#pragma unroll
        for (int mi = 0; mi < 4; ++mi)
#pragma unroll
            for (int ni = 0; ni < 4; ++ni)
                acc[mi][ni] = __builtin_amdgcn_mfma_f32_16x16x32_bf16(
                    a[mi], b[ni], acc[mi][ni], 0, 0, 0);
        __syncthreads();
    }

    int cCol  = lane & 15;
    int cRow4 = (lane >> 4) << 2;
#pragma unroll
    for (int mi = 0; mi < 4; ++mi) {
#pragma unroll
        for (int ni = 0; ni < 4; ++ni) {
#pragma unroll
            for (int r = 0; r < 4; ++r) {
                int row = m0 + wm + mi * 16 + cRow4 + r;
                int col = n0 + wn + ni * 16 + cCol;
                if (row < M) {
                    float v = acc[mi][ni][r] + bias[col];
                    if (outf) {
                        v += pe[(size_t)(row & 1023) * DD + col];
                        int orow = (row >> 10) * obs + oro + (row & 1023);
                        outf[(size_t)orow * DD + col] = v;
                    } else {
                        outb[(size_t)row * DD + col] = __float2bfloat16(v);
                    }
                }
            }
        }
    }
}

// ---------------- f32 GEMM for small matrices (M<=16) ----------------
__global__ __launch_bounds__(256) void gemm_kernel(
    const float* __restrict__ A, const float* __restrict__ W,
    const float* __restrict__ bias, float* __restrict__ out,
    int M, const float* __restrict__ res, int gelu)
{
    __shared__ float As[64][17];
    __shared__ float Bs[64][17];
    int tid = threadIdx.x;
    int tx = tid & 15, ty = tid >> 4;
    int m0 = blockIdx.y * 64;
    int n0 = blockIdx.x * 64;
    float acc[4][4] = {};
    for (int k0 = 0; k0 < DD; k0 += 16) {
#pragma unroll
        for (int r = 0; r < 4; ++r) {
            int row = ty + r * 16;
            int m = m0 + row;
            As[row][tx] = (m < M) ? A[(size_t)m * DD + k0 + tx] : 0.f;
            Bs[row][tx] = W[(size_t)(n0 + row) * DD + k0 + tx];
        }
        __syncthreads();
#pragma unroll
        for (int k = 0; k < 16; ++k) {
            float a[4], b[4];
#pragma unroll
            for (int i = 0; i < 4; ++i) a[i] = As[ty * 4 + i][k];
#pragma unroll
            for (int j = 0; j < 4; ++j) b[j] = Bs[tx * 4 + j][k];
#pragma unroll
            for (int i = 0; i < 4; ++i)
#pragma unroll
                for (int j = 0; j < 4; ++j)
                    acc[i][j] += a[i] * b[j];
        }
        __syncthreads();
    }
#pragma unroll
    for (int i = 0; i < 4; ++i) {
        int m = m0 + ty * 4 + i;
        if (m >= M) continue;
#pragma unroll
        for (int j = 0; j < 4; ++j) {
            int n = n0 + tx * 4 + j;
            float v = acc[i][j] + bias[n];
            if (gelu) v = 0.5f * v * (1.0f + erff(v * 0.70710678118654752f));
            if (res)  v += res[(size_t)m * DD + n];
            out[(size_t)m * DD + n] = v;
        }
    }
}

// ---------------- attention: one block per (b,h); wave w = query w ----------------
__global__ __launch_bounds__(256) void attn_kernel(
    const float* __restrict__ qh, const bf16* __restrict__ kh,
    const bf16* __restrict__ vh, float* __restrict__ out, int Lq)
{
    __shared__ float sc[4][LKV];
    __shared__ float qs[4][64];
    int tid = threadIdx.x;
    int lane = tid & 63;
    int w = tid >> 6;
    int bh = blockIdx.x;
    int b = bh >> 4;
    int h = bh & 15;
    int qi = w;
    bool act = qi < Lq;
    if (act) qs[w][lane] = qh[(size_t)(b * Lq + qi) * DD + h * 64 + lane];
    __syncthreads();
    if (act) {
        for (int kb = 0; kb < LKV; kb += 64) {
            int key = kb + lane;
            if (key < LKV) {
                const ushort4* kr = (const ushort4*)((const unsigned short*)kh
                    + (size_t)(b * LKV + key) * DD + h * 64);
                float s = 0.f;
#pragma unroll
                for (int d4 = 0; d4 < 16; ++d4) {
                    ushort4 kk = kr[d4];
                    s += qs[w][d4 * 4 + 0] * b2f(kk.x) + qs[w][d4 * 4 + 1] * b2f(kk.y)
                       + qs[w][d4 * 4 + 2] * b2f(kk.z) + qs[w][d4 * 4 + 3] * b2f(kk.w);
                }
                sc[w][key] = s * 0.125f;
            }
        }
        float mx = -1e30f;
        for (int key = lane; key < LKV; key += 64) mx = fmaxf(mx, sc[w][key]);
#pragma unroll
        for (int o = 32; o > 0; o >>= 1) mx = fmaxf(mx, __shfl_xor(mx, o));
        float ssum = 0.f;
        for (int key = lane; key < LKV; key += 64) {
            float e = expf(sc[w][key] - mx);
            sc[w][key] = e;
            ssum += e;
        }
        ssum = warp_sum(ssum);
        float inv = 1.f / ssum;
        const unsigned short* vbase = (const unsigned short*)vh
            + (size_t)b * LKV * DD + h * 64 + lane;
        float acc = 0.f;
        for (int key = 0; key < LKV; ++key)
            acc += sc[w][key] * b2f(vbase[(size_t)key * DD]);
        out[(size_t)(b * Lq + qi) * DD + h * 64 + lane] = acc * inv;
    }
}

// ---------------- small copies ----------------
__global__ __launch_bounds__(256) void copy_state_kernel(
    const float* __restrict__ sf, float* __restrict__ cat)
{
    int r = blockIdx.x;
    int b = r >> 2, s = r & 3;
    int tid = threadIdx.x;
#pragma unroll
    for (int i = 0; i < 4; ++i)
        cat[(size_t)(b * LKV + s) * DD + i * 256 + tid] = sf[(size_t)r * DD + i * 256 + tid];
}

__global__ __launch_bounds__(256) void copy_lolast_kernel(
    const float* __restrict__ cat, float* __restrict__ dst)
{
    int b = blockIdx.x;
    int tid = threadIdx.x;
#pragma unroll
    for (int i = 0; i < 4; ++i)
        dst[(size_t)b * DD + i * 256 + tid] =
            cat[(size_t)(b * LKV + (TT - 1)) * DD + i * 256 + tid];
}

// ---------------- slot logits ----------------
__global__ __launch_bounds__(256) void logits_kernel(
    const float* __restrict__ ln, const float* __restrict__ ctx, float* __restrict__ out)
{
    int r = blockIdx.x;
    int tid = threadIdx.x;
    float s = 0.f;
    for (int i = tid; i < DD; i += 256) s += ln[(size_t)r * DD + i] * ctx[i];
    s = warp_sum(s);
    __shared__ float a[4];
    if ((tid & 63) == 0) a[tid >> 6] = s;
    __syncthreads();
    if (tid == 0) out[r] = a[0] + a[1] + a[2] + a[3];
}

// ---------------- top-2 gate + state update ----------------
__global__ __launch_bounds__(256) void gate_kernel(
    const float* __restrict__ logits, const float* __restrict__ state_old,
    const float* __restrict__ lat2, float* __restrict__ cat_o,
    float* __restrict__ dout)
{
    int b = blockIdx.x;
    int tid = threadIdx.x;
    __shared__ float alpha[NS];
    if (tid == 0) {
        float l[NS];
        for (int s = 0; s < NS; ++s) l[s] = logits[b * NS + s];
        int i0 = 0;
        for (int s = 1; s < NS; ++s) if (l[s] > l[i0]) i0 = s;
        int i1 = (i0 == 0) ? 1 : 0;
        for (int s = 0; s < NS; ++s) if (s != i0 && l[s] > l[i1]) i1 = s;
        float mx = fmaxf(l[i0], l[i1]);
        float e0 = expf(l[i0] - mx), e1 = expf(l[i1] - mx);
        float inv = 1.f / (e0 + e1);
        for (int s = 0; s < NS; ++s) alpha[s] = 0.f;
        alpha[i0] = e0 * inv;
        alpha[i1] += e1 * inv;
        dout[4096 + b * 2 + 0] = (float)i0;
        dout[4096 + b * 2 + 1] = (float)i1;
    }
    __syncthreads();
    for (int idx = tid; idx < NS * DD; idx += 256) {
        int s = idx >> 10;
        int d = idx & 1023;
        float so = state_old[(size_t)b * NS * DD + idx];
        float lt = lat2[(size_t)b * NS * DD + idx];
        float ns = 0.6f * so + 0.4f * alpha[s] * tanhf(lt);
        cat_o[(size_t)(b * LKV + TT + s) * DD + d] = ns;
        dout[4104 + b * NS * DD + idx] = ns;
    }
}

extern "C" void kernel_launch(void* const* d_in, const int* in_sizes, int n_in,
                              void* d_out, int out_size, void* d_ws, size_t ws_size,
                              hipStream_t stream)
{
    const float* x        = (const float*)d_in[0];
    const float* state0   = (const float*)d_in[1];
    const float* se_W     = (const float*)d_in[2];
    const float* se_b     = (const float*)d_in[3];
    const float* s_Wq     = (const float*)d_in[4];
    const float* s_bq     = (const float*)d_in[5];
    const float* s_Wk     = (const float*)d_in[6];
    const float* s_bk     = (const float*)d_in[7];
    const float* s_Wv     = (const float*)d_in[8];
    const float* s_bv     = (const float*)d_in[9];
    const float* s_Wo     = (const float*)d_in[10];
    const float* s_bo     = (const float*)d_in[11];
    const float* s_lnq_g  = (const float*)d_in[12];
    const float* s_lnq_b  = (const float*)d_in[13];
    const float* s_lnkv_g = (const float*)d_in[14];
    const float* s_lnkv_b = (const float*)d_in[15];
    const float* s_fc1_W  = (const float*)d_in[16];
    const float* s_fc1_b  = (const float*)d_in[17];
    const float* s_fc2_W  = (const float*)d_in[18];
    const float* s_fc2_b  = (const float*)d_in[19];
    const float* s_lnffn_g= (const float*)d_in[20];
    const float* s_lnffn_b= (const float*)d_in[21];
    const float* s_lnslot_g=(const float*)d_in[22];
    const float* s_lnslot_b=(const float*)d_in[23];
    const float* slot_ctx = (const float*)d_in[24];
    const float* oe_W     = (const float*)d_in[25];
    const float* oe_b     = (const float*)d_in[26];
    const float* o_Wq     = (const float*)d_in[27];
    const float* o_bq     = (const float*)d_in[28];
    const float* o_Wk     = (const float*)d_in[29];
    const float* o_bk     = (const float*)d_in[30];
    const float* o_Wv     = (const float*)d_in[31];
    const float* o_bv     = (const float*)d_in[32];
    const float* o_Wo     = (const float*)d_in[33];
    const float* o_bo     = (const float*)d_in[34];
    const float* o_lnq_g  = (const float*)d_in[35];
    const float* o_lnq_b  = (const float*)d_in[36];
    const float* o_lnkv_g = (const float*)d_in[37];
    const float* o_lnkv_b = (const float*)d_in[38];
    const float* o_fc1_W  = (const float*)d_in[39];
    const float* o_fc1_b  = (const float*)d_in[40];
    const float* o_fc2_W  = (const float*)d_in[41];
    const float* o_fc2_b  = (const float*)d_in[42];
    const float* o_lnffn_g= (const float*)d_in[43];
    const float* o_lnffn_b= (const float*)d_in[44];
    const float* op_W     = (const float*)d_in[45];
    const float* op_b     = (const float*)d_in[46];

    float* ws  = (float*)d_ws;
    float* pe   = ws;                        // 1,048,576 f32
    float* cat  = ws + 1048576;              // 4,210,688 f32
    bf16*  lnbb = (bf16*)(ws + 5259264);     // 4224*1024 bf16 = 2,162,688 f32 slots
    bf16*  kh   = (bf16*)(ws + 7421952);     // 4112*1024 bf16 = 2,105,344 slots
    bf16*  vh   = (bf16*)(ws + 9527296);     // 2,105,344 slots
    bf16*  xb   = (bf16*)(ws + 11632640);    // 4096*1024 bf16 = 2,097,152 slots
    bf16*  wb   = (bf16*)(ws + 13729792);    // 6 * 1M bf16 = 3,145,728 slots
    bf16*  seWb = wb;
    bf16*  oeWb = wb + 1048576;
    bf16*  sWkb = wb + 2097152;
    bf16*  sWvb = wb + 3145728;
    bf16*  oWkb = wb + 4194304;
    bf16*  oWvb = wb + 5242880;
    float* sm   = ws + 16875520;
    float* q_s    = sm;
    float* qh_s   = sm + 16384;
    float* attn_s = sm + 32768;
    float* lat1   = sm + 49152;
    float* hffn   = sm + 65536;
    float* g1     = sm + 81920;
    float* lat2   = sm + 98304;
    float* lnslot = sm + 114688;
    float* logitsb= sm + 131072;
    float* q2     = sm + 131136;
    float* q2h    = q2 + 4096;
    float* attn2  = q2h + 4096;
    float* lo_last= attn2 + 4096;
    float* lo1    = lo_last + 4096;
    float* h2     = lo1 + 4096;
    float* g2     = h2 + 4096;
    float* lo2    = g2 + 4096;
    float* out = (float*)d_out;

    dim3 blk(256);
    dim3 gBig(8, 32);    // N=1024, M=4096
    dim3 gBigP(8, 33);   // M=4112 padded

    // ---- conversions + PE ----
    cvt_kernel<<<4096, blk, 0, stream>>>(x, xb);
    cvt_kernel<<<1024, blk, 0, stream>>>(se_W, seWb);
    cvt_kernel<<<1024, blk, 0, stream>>>(oe_W, oeWb);
    cvt_kernel<<<1024, blk, 0, stream>>>(s_Wk, sWkb);
    cvt_kernel<<<1024, blk, 0, stream>>>(s_Wv, sWvb);
    cvt_kernel<<<1024, blk, 0, stream>>>(o_Wk, oWkb);
    cvt_kernel<<<1024, blk, 0, stream>>>(o_Wv, oWvb);
    pe_kernel<<<TT, blk, 0, stream>>>(pe);

    // ---- state branch ----
    copy_state_kernel<<<16, blk, 0, stream>>>(state0, cat);
    mfma_gemm_kernel<<<gBig, blk, 0, stream>>>(xb, seWb, se_b, cat, nullptr,
        4096, LKV, NS, pe);                                            // lx -> cat rows b*1028+4+t
    ln_kernel<<<16, blk, 0, stream>>>(state0, q_s, s_lnq_g, s_lnq_b, 0, 1);
    ln_bf16_kernel<<<4112, blk, 0, stream>>>(cat, lnbb, s_lnkv_g, s_lnkv_b);
    gemm_kernel<<<dim3(16, 1), blk, 0, stream>>>(q_s, s_Wq, s_bq, qh_s, 16, nullptr, 0);
    mfma_gemm_kernel<<<gBigP, blk, 0, stream>>>(lnbb, sWkb, s_bk, nullptr, kh,
        4112, 0, 0, nullptr);
    mfma_gemm_kernel<<<gBigP, blk, 0, stream>>>(lnbb, sWvb, s_bv, nullptr, vh,
        4112, 0, 0, nullptr);
    attn_kernel<<<64, blk, 0, stream>>>(qh_s, kh, vh, attn_s, 4);
    gemm_kernel<<<dim3(16, 1), blk, 0, stream>>>(attn_s, s_Wo, s_bo, lat1, 16, state0, 0);
    ln_kernel<<<16, blk, 0, stream>>>(lat1, hffn, s_lnffn_g, s_lnffn_b, 0, 1);
    gemm_kernel<<<dim3(16, 1), blk, 0, stream>>>(hffn, s_fc1_W, s_fc1_b, g1, 16, nullptr, 1);
    gemm_kernel<<<dim3(16, 1), blk, 0, stream>>>(g1, s_fc2_W, s_fc2_b, lat2, 16, lat1, 0);
    ln_kernel<<<16, blk, 0, stream>>>(lat2, lnslot, s_lnslot_g, s_lnslot_b, 0, 1);
    logits_kernel<<<16, blk, 0, stream>>>(lnslot, slot_ctx, logitsb);
    gate_kernel<<<NB, blk, 0, stream>>>(logitsb, state0, lat2, cat, out);

    // ---- out branch ----
    mfma_gemm_kernel<<<gBig, blk, 0, stream>>>(xb, oeWb, oe_b, cat, nullptr,
        4096, LKV, 0, pe);                                             // lo -> cat rows b*1028+t
    ln_kernel<<<NB, blk, 0, stream>>>(cat, q2, o_lnq_g, o_lnq_b, TT - 1, LKV);
    ln_bf16_kernel<<<4112, blk, 0, stream>>>(cat, lnbb, o_lnkv_g, o_lnkv_b);
    gemm_kernel<<<dim3(16, 1), blk, 0, stream>>>(q2, o_Wq, o_bq, q2h, 4, nullptr, 0);
    mfma_gemm_kernel<<<gBigP, blk, 0, stream>>>(lnbb, oWkb, o_bk, nullptr, kh,
        4112, 0, 0, nullptr);
    mfma_gemm_kernel<<<gBigP, blk, 0, stream>>>(lnbb, oWvb, o_bv, nullptr, vh,
        4112, 0, 0, nullptr);
    attn_kernel<<<64, blk, 0, stream>>>(q2h, kh, vh, attn2, 1);
    copy_lolast_kernel<<<NB, blk, 0, stream>>>(cat, lo_last);
    gemm_kernel<<<dim3(16, 1), blk, 0, stream>>>(attn2, o_Wo, o_bo, lo1, 4, lo_last, 0);
    ln_kernel<<<NB, blk, 0, stream>>>(lo1, h2, o_lnffn_g, o_lnffn_b, 0, 1);
    gemm_kernel<<<dim3(16, 1), blk, 0, stream>>>(h2, o_fc1_W, o_fc1_b, g2, 4, nullptr, 1);
    gemm_kernel<<<dim3(16, 1), blk, 0, stream>>>(g2, o_fc2_W, o_fc2_b, lo2, 4, lo1, 0);
    gemm_kernel<<<dim3(16, 1), blk, 0, stream>>>(lo2, op_W, op_b, out, 4, nullptr, 0);
}

// Round 4
// 513.129 us; speedup vs baseline: 5.4083x; 2.8294x over previous
//
#include <hip/hip_runtime.h>
#include <hip/hip_bf16.h>

#define DD 1024
#define NB 4
#define TT 1024
#define NH 16
#define NS 4
#define LKV 1028   // NS + TT

typedef __hip_bfloat16 bf16;
typedef __attribute__((ext_vector_type(8))) short short8;
typedef __attribute__((ext_vector_type(4))) float f32x4;

#define GLD16(gp, lp) __builtin_amdgcn_global_load_lds( \
    (const __attribute__((address_space(1))) unsigned int*)(const void*)(gp), \
    (__attribute__((address_space(3))) unsigned int*)(void*)(lp), 16, 0, 0)

__device__ __forceinline__ float warp_sum(float v) {
#pragma unroll
    for (int o = 32; o > 0; o >>= 1) v += __shfl_xor(v, o);
    return v;
}

__device__ __forceinline__ float b2f(unsigned short u) {
    union { unsigned int i; float f; } x; x.i = ((unsigned)u) << 16; return x.f;
}

// ---------------- f32 -> bf16 conversion (4 elems/thread) ----------------
__global__ __launch_bounds__(256) void cvt_kernel(
    const float* __restrict__ in, bf16* __restrict__ out)
{
    int i = (blockIdx.x * 256 + threadIdx.x) * 4;
    float4 v = *(const float4*)(in + i);
    out[i + 0] = __float2bfloat16(v.x);
    out[i + 1] = __float2bfloat16(v.y);
    out[i + 2] = __float2bfloat16(v.z);
    out[i + 3] = __float2bfloat16(v.w);
}

// ---------------- positional encoding table ----------------
__global__ __launch_bounds__(256) void pe_kernel(float* __restrict__ pe) {
    int t = blockIdx.x;
    int tid = threadIdx.x;
#pragma unroll
    for (int i = 0; i < 2; ++i) {
        int j = i * 256 + tid;                       // 0..511
        float ang = (float)t * exp2f(-(float)j * (1.0f / 256.0f)); // t * 4^(-j/512)
        pe[(size_t)t * DD + j]        = sinf(ang);
        pe[(size_t)t * DD + 512 + j]  = cosf(ang);
    }
}

// ---------------- LayerNorm f32 out ----------------
__global__ __launch_bounds__(256) void ln_kernel(
    const float* __restrict__ in, float* __restrict__ out,
    const float* __restrict__ g, const float* __restrict__ b,
    int row0, int rstride)
{
    int r = blockIdx.x;
    int tid = threadIdx.x;
    size_t base = (size_t)(row0 + (size_t)r * rstride) * DD;
    float v[4];
    float s1 = 0.f, s2 = 0.f;
#pragma unroll
    for (int i = 0; i < 4; ++i) {
        v[i] = in[base + i * 256 + tid];
        s1 += v[i]; s2 += v[i] * v[i];
    }
    s1 = warp_sum(s1); s2 = warp_sum(s2);
    __shared__ float a1[4], a2[4];
    int w = tid >> 6;
    if ((tid & 63) == 0) { a1[w] = s1; a2[w] = s2; }
    __syncthreads();
    s1 = a1[0] + a1[1] + a1[2] + a1[3];
    s2 = a2[0] + a2[1] + a2[2] + a2[3];
    float mu  = s1 * (1.0f / DD);
    float var = s2 * (1.0f / DD) - mu * mu;
    var = var < 0.f ? 0.f : var;
    float rs = rsqrtf(var + 1e-5f);
#pragma unroll
    for (int i = 0; i < 4; ++i) {
        int c = i * 256 + tid;
        out[(size_t)r * DD + c] = (v[i] - mu) * rs * g[c] + b[c];
    }
}

// ---------------- LayerNorm bf16 out ----------------
__global__ __launch_bounds__(256) void ln_bf16_kernel(
    const float* __restrict__ in, bf16* __restrict__ out,
    const float* __restrict__ g, const float* __restrict__ b)
{
    int r = blockIdx.x;
    int tid = threadIdx.x;
    size_t base = (size_t)r * DD;
    float v[4];
    float s1 = 0.f, s2 = 0.f;
#pragma unroll
    for (int i = 0; i < 4; ++i) {
        v[i] = in[base + i * 256 + tid];
        s1 += v[i]; s2 += v[i] * v[i];
    }
    s1 = warp_sum(s1); s2 = warp_sum(s2);
    __shared__ float a1[4], a2[4];
    int w = tid >> 6;
    if ((tid & 63) == 0) { a1[w] = s1; a2[w] = s2; }
    __syncthreads();
    s1 = a1[0] + a1[1] + a1[2] + a1[3];
    s2 = a2[0] + a2[1] + a2[2] + a2[3];
    float mu  = s1 * (1.0f / DD);
    float var = s2 * (1.0f / DD) - mu * mu;
    var = var < 0.f ? 0.f : var;
    float rs = rsqrtf(var + 1e-5f);
#pragma unroll
    for (int i = 0; i < 4; ++i) {
        int c = i * 256 + tid;
        out[base + c] = __float2bfloat16((v[i] - mu) * rs * g[c] + b[c]);
    }
}

// ---------------- bf16 MFMA GEMM (128x128 tile, BK=32, 4 waves) ----------------
__global__ __launch_bounds__(256) void mfma_gemm_kernel(
    const bf16* __restrict__ A, const bf16* __restrict__ W,
    const float* __restrict__ bias,
    float* __restrict__ outf, bf16* __restrict__ outb,
    int M, int obs, int oro, const float* __restrict__ pe)
{
    __shared__ bf16 As[128 * 32];
    __shared__ bf16 Ws[128 * 32];
    int tid  = threadIdx.x;
    int lane = tid & 63;
    int wave = tid >> 6;
    int m0 = blockIdx.y * 128;
    int n0 = blockIdx.x * 128;
    int wm = (wave >> 1) << 6;     // 0 / 64
    int wn = (wave & 1) << 6;      // 0 / 64

    f32x4 acc[4][4] = {};

    int soff  = wave * 1024 + lane * 16;   // issue-0 byte offset
    int srow  = soff >> 6;                 // row in tile (64B rows)
    int scol  = (soff & 63) >> 1;          // bf16 column
    char* lA0 = (char*)As + wave * 1024;
    char* lA1 = (char*)As + 4096 + wave * 1024;
    char* lW0 = (char*)Ws + wave * 1024;
    char* lW1 = (char*)Ws + 4096 + wave * 1024;

    int fRow = lane & 15;
    int kOff = (lane >> 4) << 3;           // 0,8,16,24

    for (int k0 = 0; k0 < DD; k0 += 32) {
        GLD16(A + (size_t)(m0 + srow) * DD + k0 + scol,      lA0);
        GLD16(A + (size_t)(m0 + 64 + srow) * DD + k0 + scol, lA1);
        GLD16(W + (size_t)(n0 + srow) * DD + k0 + scol,      lW0);
        GLD16(W + (size_t)(n0 + 64 + srow) * DD + k0 + scol, lW1);
        __syncthreads();
        short8 a[4], b[4];
#pragma unroll
        for (int mi = 0; mi < 4; ++mi)
            a[mi] = *(const short8*)(As + (wm + mi * 16 + fRow) * 32 + kOff);
#pragma unroll
        for (int ni = 0; ni < 4; ++ni)
            b[ni] = *(const short8*)(Ws + (wn + ni * 16 + fRow) * 32 + kOff);
#pragma unroll
        for (int mi = 0; mi < 4; ++mi)
#pragma unroll
            for (int ni = 0; ni < 4; ++ni)
                acc[mi][ni] = __builtin_amdgcn_mfma_f32_16x16x32_bf16(
                    a[mi], b[ni], acc[mi][ni], 0, 0, 0);
        __syncthreads();
    }

    int cCol  = lane & 15;
    int cRow4 = (lane >> 4) << 2;
#pragma unroll
    for (int mi = 0; mi < 4; ++mi) {
#pragma unroll
        for (int ni = 0; ni < 4; ++ni) {
#pragma unroll
            for (int r = 0; r < 4; ++r) {
                int row = m0 + wm + mi * 16 + cRow4 + r;
                int col = n0 + wn + ni * 16 + cCol;
                if (row < M) {
                    float v = acc[mi][ni][r] + bias[col];
                    if (outf) {
                        v += pe[(size_t)(row & 1023) * DD + col];
                        int orow = (row >> 10) * obs + oro + (row & 1023);
                        outf[(size_t)orow * DD + col] = v;
                    } else {
                        outb[(size_t)row * DD + col] = __float2bfloat16(v);
                    }
                }
            }
        }
    }
}

// ---------------- small GEMM (M<=16): one wave per output column ----------------
// C[m][n] = dot(A[m,:], W[n,:]) + bias[n]; optional gelu then residual.
// grid 256 blocks x 256 thr; wave w of block bk handles column n = bk*4+w.
template<int M>
__global__ __launch_bounds__(256) void small_gemm_kernel(
    const float* __restrict__ A, const float* __restrict__ W,
    const float* __restrict__ bias, float* __restrict__ out,
    const float* __restrict__ res, int gelu)
{
    __shared__ float As[M * DD];
    int tid = threadIdx.x;
#pragma unroll
    for (int i = 0; i < M; ++i) {
        int idx = (i * 256 + tid) * 4;
        *(float4*)(As + idx) = *(const float4*)(A + idx);
    }
    __syncthreads();
    int lane = tid & 63;
    int w = tid >> 6;
    int n = blockIdx.x * 4 + w;
    const float* Wr = W + (size_t)n * DD;
    float acc[M] = {};
#pragma unroll
    for (int j = 0; j < 4; ++j) {
        float4 wv = *(const float4*)(Wr + j * 256 + lane * 4);
#pragma unroll
        for (int m = 0; m < M; ++m) {
            float4 av = *(const float4*)(As + m * DD + j * 256 + lane * 4);
            acc[m] += av.x * wv.x + av.y * wv.y + av.z * wv.z + av.w * wv.w;
        }
    }
#pragma unroll
    for (int m = 0; m < M; ++m) acc[m] = warp_sum(acc[m]);
    if (lane == 0) {
#pragma unroll
        for (int m = 0; m < M; ++m) {
            float v = acc[m] + bias[n];
            if (gelu) v = 0.5f * v * (1.0f + erff(v * 0.70710678118654752f));
            if (res)  v += res[(size_t)m * DD + n];
            out[(size_t)m * DD + n] = v;
        }
    }
}

// ---------------- attention: one block per (b,h); wave w = query w ----------------
__global__ __launch_bounds__(256) void attn_kernel(
    const float* __restrict__ qh, const bf16* __restrict__ kh,
    const bf16* __restrict__ vh, float* __restrict__ out, int Lq)
{
    __shared__ float sc[4][LKV];
    __shared__ float qs[4][64];
    int tid = threadIdx.x;
    int lane = tid & 63;
    int w = tid >> 6;
    int bh = blockIdx.x;
    int b = bh >> 4;
    int h = bh & 15;
    int qi = w;
    bool act = qi < Lq;
    if (act) qs[w][lane] = qh[(size_t)(b * Lq + qi) * DD + h * 64 + lane];
    __syncthreads();
    if (act) {
        for (int kb = 0; kb < LKV; kb += 64) {
            int key = kb + lane;
            if (key < LKV) {
                const ushort4* kr = (const ushort4*)((const unsigned short*)kh
                    + (size_t)(b * LKV + key) * DD + h * 64);
                float s = 0.f;
#pragma unroll
                for (int d4 = 0; d4 < 16; ++d4) {
                    ushort4 kk = kr[d4];
                    s += qs[w][d4 * 4 + 0] * b2f(kk.x) + qs[w][d4 * 4 + 1] * b2f(kk.y)
                       + qs[w][d4 * 4 + 2] * b2f(kk.z) + qs[w][d4 * 4 + 3] * b2f(kk.w);
                }
                sc[w][key] = s * 0.125f;
            }
        }
        float mx = -1e30f;
        for (int key = lane; key < LKV; key += 64) mx = fmaxf(mx, sc[w][key]);
#pragma unroll
        for (int o = 32; o > 0; o >>= 1) mx = fmaxf(mx, __shfl_xor(mx, o));
        float ssum = 0.f;
        for (int key = lane; key < LKV; key += 64) {
            float e = expf(sc[w][key] - mx);
            sc[w][key] = e;
            ssum += e;
        }
        ssum = warp_sum(ssum);
        float inv = 1.f / ssum;
        const unsigned short* vbase = (const unsigned short*)vh
            + (size_t)b * LKV * DD + h * 64 + lane;
        float acc = 0.f;
        for (int key = 0; key < LKV; ++key)
            acc += sc[w][key] * b2f(vbase[(size_t)key * DD]);
        out[(size_t)(b * Lq + qi) * DD + h * 64 + lane] = acc * inv;
    }
}

// ---------------- small copies ----------------
__global__ __launch_bounds__(256) void copy_state_kernel(
    const float* __restrict__ sf, float* __restrict__ cat)
{
    int r = blockIdx.x;
    int b = r >> 2, s = r & 3;
    int tid = threadIdx.x;
#pragma unroll
    for (int i = 0; i < 4; ++i)
        cat[(size_t)(b * LKV + s) * DD + i * 256 + tid] = sf[(size_t)r * DD + i * 256 + tid];
}

__global__ __launch_bounds__(256) void copy_lolast_kernel(
    const float* __restrict__ cat, float* __restrict__ dst)
{
    int b = blockIdx.x;
    int tid = threadIdx.x;
#pragma unroll
    for (int i = 0; i < 4; ++i)
        dst[(size_t)b * DD + i * 256 + tid] =
            cat[(size_t)(b * LKV + (TT - 1)) * DD + i * 256 + tid];
}

// ---------------- slot logits ----------------
__global__ __launch_bounds__(256) void logits_kernel(
    const float* __restrict__ ln, const float* __restrict__ ctx, float* __restrict__ out)
{
    int r = blockIdx.x;
    int tid = threadIdx.x;
    float s = 0.f;
    for (int i = tid; i < DD; i += 256) s += ln[(size_t)r * DD + i] * ctx[i];
    s = warp_sum(s);
    __shared__ float a[4];
    if ((tid & 63) == 0) a[tid >> 6] = s;
    __syncthreads();
    if (tid == 0) out[r] = a[0] + a[1] + a[2] + a[3];
}

// ---------------- top-2 gate + state update ----------------
__global__ __launch_bounds__(256) void gate_kernel(
    const float* __restrict__ logits, const float* __restrict__ state_old,
    const float* __restrict__ lat2, float* __restrict__ cat_o,
    float* __restrict__ dout)
{
    int b = blockIdx.x;
    int tid = threadIdx.x;
    __shared__ float alpha[NS];
    if (tid == 0) {
        float l[NS];
        for (int s = 0; s < NS; ++s) l[s] = logits[b * NS + s];
        int i0 = 0;
        for (int s = 1; s < NS; ++s) if (l[s] > l[i0]) i0 = s;
        int i1 = (i0 == 0) ? 1 : 0;
        for (int s = 0; s < NS; ++s) if (s != i0 && l[s] > l[i1]) i1 = s;
        float mx = fmaxf(l[i0], l[i1]);
        float e0 = expf(l[i0] - mx), e1 = expf(l[i1] - mx);
        float inv = 1.f / (e0 + e1);
        for (int s = 0; s < NS; ++s) alpha[s] = 0.f;
        alpha[i0] = e0 * inv;
        alpha[i1] += e1 * inv;
        dout[4096 + b * 2 + 0] = (float)i0;
        dout[4096 + b * 2 + 1] = (float)i1;
    }
    __syncthreads();
    for (int idx = tid; idx < NS * DD; idx += 256) {
        int s = idx >> 10;
        int d = idx & 1023;
        float so = state_old[(size_t)b * NS * DD + idx];
        float lt = lat2[(size_t)b * NS * DD + idx];
        float ns = 0.6f * so + 0.4f * alpha[s] * tanhf(lt);
        cat_o[(size_t)(b * LKV + TT + s) * DD + d] = ns;
        dout[4104 + b * NS * DD + idx] = ns;
    }
}

extern "C" void kernel_launch(void* const* d_in, const int* in_sizes, int n_in,
                              void* d_out, int out_size, void* d_ws, size_t ws_size,
                              hipStream_t stream)
{
    const float* x        = (const float*)d_in[0];
    const float* state0   = (const float*)d_in[1];
    const float* se_W     = (const float*)d_in[2];
    const float* se_b     = (const float*)d_in[3];
    const float* s_Wq     = (const float*)d_in[4];
    const float* s_bq     = (const float*)d_in[5];
    const float* s_Wk     = (const float*)d_in[6];
    const float* s_bk     = (const float*)d_in[7];
    const float* s_Wv     = (const float*)d_in[8];
    const float* s_bv     = (const float*)d_in[9];
    const float* s_Wo     = (const float*)d_in[10];
    const float* s_bo     = (const float*)d_in[11];
    const float* s_lnq_g  = (const float*)d_in[12];
    const float* s_lnq_b  = (const float*)d_in[13];
    const float* s_lnkv_g = (const float*)d_in[14];
    const float* s_lnkv_b = (const float*)d_in[15];
    const float* s_fc1_W  = (const float*)d_in[16];
    const float* s_fc1_b  = (const float*)d_in[17];
    const float* s_fc2_W  = (const float*)d_in[18];
    const float* s_fc2_b  = (const float*)d_in[19];
    const float* s_lnffn_g= (const float*)d_in[20];
    const float* s_lnffn_b= (const float*)d_in[21];
    const float* s_lnslot_g=(const float*)d_in[22];
    const float* s_lnslot_b=(const float*)d_in[23];
    const float* slot_ctx = (const float*)d_in[24];
    const float* oe_W     = (const float*)d_in[25];
    const float* oe_b     = (const float*)d_in[26];
    const float* o_Wq     = (const float*)d_in[27];
    const float* o_bq     = (const float*)d_in[28];
    const float* o_Wk     = (const float*)d_in[29];
    const float* o_bk     = (const float*)d_in[30];
    const float* o_Wv     = (const float*)d_in[31];
    const float* o_bv     = (const float*)d_in[32];
    const float* o_Wo     = (const float*)d_in[33];
    const float* o_bo     = (const float*)d_in[34];
    const float* o_lnq_g  = (const float*)d_in[35];
    const float* o_lnq_b  = (const float*)d_in[36];
    const float* o_lnkv_g = (const float*)d_in[37];
    const float* o_lnkv_b = (const float*)d_in[38];
    const float* o_fc1_W  = (const float*)d_in[39];
    const float* o_fc1_b  = (const float*)d_in[40];
    const float* o_fc2_W  = (const float*)d_in[41];
    const float* o_fc2_b  = (const float*)d_in[42];
    const float* o_lnffn_g= (const float*)d_in[43];
    const float* o_lnffn_b= (const float*)d_in[44];
    const float* op_W     = (const float*)d_in[45];
    const float* op_b     = (const float*)d_in[46];

    float* ws  = (float*)d_ws;
    float* pe   = ws;                        // 1,048,576 f32
    float* cat  = ws + 1048576;              // 4,210,688 f32
    bf16*  lnbb = (bf16*)(ws + 5259264);     // 4224*1024 bf16
    bf16*  kh   = (bf16*)(ws + 7421952);     // 4112*1024 bf16
    bf16*  vh   = (bf16*)(ws + 9527296);
    bf16*  xb   = (bf16*)(ws + 11632640);    // 4096*1024 bf16
    bf16*  wb   = (bf16*)(ws + 13729792);    // 6 x 1M bf16
    bf16*  seWb = wb;
    bf16*  oeWb = wb + 1048576;
    bf16*  sWkb = wb + 2097152;
    bf16*  sWvb = wb + 3145728;
    bf16*  oWkb = wb + 4194304;
    bf16*  oWvb = wb + 5242880;
    float* sm   = ws + 16875520;
    float* q_s    = sm;
    float* qh_s   = sm + 16384;
    float* attn_s = sm + 32768;
    float* lat1   = sm + 49152;
    float* hffn   = sm + 65536;
    float* g1     = sm + 81920;
    float* lat2   = sm + 98304;
    float* lnslot = sm + 114688;
    float* logitsb= sm + 131072;
    float* q2     = sm + 131136;
    float* q2h    = q2 + 4096;
    float* attn2  = q2h + 4096;
    float* lo_last= attn2 + 4096;
    float* lo1    = lo_last + 4096;
    float* h2     = lo1 + 4096;
    float* g2     = h2 + 4096;
    float* lo2    = g2 + 4096;
    float* out = (float*)d_out;

    dim3 blk(256);
    dim3 gBig(8, 32);    // N=1024, M=4096
    dim3 gBigP(8, 33);   // M=4112 padded
    dim3 gSm(256);

    // ---- conversions + PE ----
    cvt_kernel<<<4096, blk, 0, stream>>>(x, xb);
    cvt_kernel<<<1024, blk, 0, stream>>>(se_W, seWb);
    cvt_kernel<<<1024, blk, 0, stream>>>(oe_W, oeWb);
    cvt_kernel<<<1024, blk, 0, stream>>>(s_Wk, sWkb);
    cvt_kernel<<<1024, blk, 0, stream>>>(s_Wv, sWvb);
    cvt_kernel<<<1024, blk, 0, stream>>>(o_Wk, oWkb);
    cvt_kernel<<<1024, blk, 0, stream>>>(o_Wv, oWvb);
    pe_kernel<<<TT, blk, 0, stream>>>(pe);

    // ---- state branch ----
    copy_state_kernel<<<16, blk, 0, stream>>>(state0, cat);
    mfma_gemm_kernel<<<gBig, blk, 0, stream>>>(xb, seWb, se_b, cat, nullptr,
        4096, LKV, NS, pe);                                            // lx -> cat rows b*1028+4+t
    ln_kernel<<<16, blk, 0, stream>>>(state0, q_s, s_lnq_g, s_lnq_b, 0, 1);
    ln_bf16_kernel<<<4112, blk, 0, stream>>>(cat, lnbb, s_lnkv_g, s_lnkv_b);
    small_gemm_kernel<16><<<gSm, blk, 0, stream>>>(q_s, s_Wq, s_bq, qh_s, nullptr, 0);
    mfma_gemm_kernel<<<gBigP, blk, 0, stream>>>(lnbb, sWkb, s_bk, nullptr, kh,
        4112, 0, 0, nullptr);
    mfma_gemm_kernel<<<gBigP, blk, 0, stream>>>(lnbb, sWvb, s_bv, nullptr, vh,
        4112, 0, 0, nullptr);
    attn_kernel<<<64, blk, 0, stream>>>(qh_s, kh, vh, attn_s, 4);
    small_gemm_kernel<16><<<gSm, blk, 0, stream>>>(attn_s, s_Wo, s_bo, lat1, state0, 0);
    ln_kernel<<<16, blk, 0, stream>>>(lat1, hffn, s_lnffn_g, s_lnffn_b, 0, 1);
    small_gemm_kernel<16><<<gSm, blk, 0, stream>>>(hffn, s_fc1_W, s_fc1_b, g1, nullptr, 1);
    small_gemm_kernel<16><<<gSm, blk, 0, stream>>>(g1, s_fc2_W, s_fc2_b, lat2, lat1, 0);
    ln_kernel<<<16, blk, 0, stream>>>(lat2, lnslot, s_lnslot_g, s_lnslot_b, 0, 1);
    logits_kernel<<<16, blk, 0, stream>>>(lnslot, slot_ctx, logitsb);
    gate_kernel<<<NB, blk, 0, stream>>>(logitsb, state0, lat2, cat, out);

    // ---- out branch ----
    mfma_gemm_kernel<<<gBig, blk, 0, stream>>>(xb, oeWb, oe_b, cat, nullptr,
        4096, LKV, 0, pe);                                             // lo -> cat rows b*1028+t
    ln_kernel<<<NB, blk, 0, stream>>>(cat, q2, o_lnq_g, o_lnq_b, TT - 1, LKV);
    ln_bf16_kernel<<<4112, blk, 0, stream>>>(cat, lnbb, o_lnkv_g, o_lnkv_b);
    small_gemm_kernel<4><<<gSm, blk, 0, stream>>>(q2, o_Wq, o_bq, q2h, nullptr, 0);
    mfma_gemm_kernel<<<gBigP, blk, 0, stream>>>(lnbb, oWkb, o_bk, nullptr, kh,
        4112, 0, 0, nullptr);
    mfma_gemm_kernel<<<gBigP, blk, 0, stream>>>(lnbb, oWvb, o_bv, nullptr, vh,
        4112, 0, 0, nullptr);
    attn_kernel<<<64, blk, 0, stream>>>(q2h, kh, vh, attn2, 1);
    copy_lolast_kernel<<<NB, blk, 0, stream>>>(cat, lo_last);
    small_gemm_kernel<4><<<gSm, blk, 0, stream>>>(attn2, o_Wo, o_bo, lo1, lo_last, 0);
    ln_kernel<<<NB, blk, 0, stream>>>(lo1, h2, o_lnffn_g, o_lnffn_b, 0, 1);
    small_gemm_kernel<4><<<gSm, blk, 0, stream>>>(h2, o_fc1_W, o_fc1_b, g2, nullptr, 1);
    small_gemm_kernel<4><<<gSm, blk, 0, stream>>>(g2, o_fc2_W, o_fc2_b, lo2, lo1, 0);
    small_gemm_kernel<4><<<gSm, blk, 0, stream>>>(lo2, op_W, op_b, out, nullptr, 0);
}

// Round 5
// 391.327 us; speedup vs baseline: 7.0917x; 1.3113x over previous
//
#include <hip/hip_runtime.h>
#include <hip/hip_bf16.h>

#define DD 1024
#define NB 4
#define TT 1024
#define NH 16
#define NS 4
#define LKV 1028   // NS + TT
#define NCH 4
#define CHS 257    // keys per chunk (4*257 = 1028)

typedef __hip_bfloat16 bf16;
typedef __attribute__((ext_vector_type(8))) short short8;
typedef __attribute__((ext_vector_type(4))) float f32x4;

#define GLD16(gp, lp) __builtin_amdgcn_global_load_lds( \
    (const __attribute__((address_space(1))) unsigned int*)(const void*)(gp), \
    (__attribute__((address_space(3))) unsigned int*)(void*)(lp), 16, 0, 0)

__device__ __forceinline__ float warp_sum(float v) {
#pragma unroll
    for (int o = 32; o > 0; o >>= 1) v += __shfl_xor(v, o);
    return v;
}

__device__ __forceinline__ float b2f(unsigned short u) {
    union { unsigned int i; float f; } x; x.i = ((unsigned)u) << 16; return x.f;
}

// ---------------- f32 -> bf16 conversion (4 elems/thread) ----------------
__global__ __launch_bounds__(256) void cvt_kernel(
    const float* __restrict__ in, bf16* __restrict__ out)
{
    int i = (blockIdx.x * 256 + threadIdx.x) * 4;
    float4 v = *(const float4*)(in + i);
    out[i + 0] = __float2bfloat16(v.x);
    out[i + 1] = __float2bfloat16(v.y);
    out[i + 2] = __float2bfloat16(v.z);
    out[i + 3] = __float2bfloat16(v.w);
}

// ---------------- positional encoding table ----------------
__global__ __launch_bounds__(256) void pe_kernel(float* __restrict__ pe) {
    int t = blockIdx.x;
    int tid = threadIdx.x;
#pragma unroll
    for (int i = 0; i < 2; ++i) {
        int j = i * 256 + tid;                       // 0..511
        float ang = (float)t * exp2f(-(float)j * (1.0f / 256.0f)); // t * 4^(-j/512)
        pe[(size_t)t * DD + j]        = sinf(ang);
        pe[(size_t)t * DD + 512 + j]  = cosf(ang);
    }
}

// ---------------- LayerNorm f32 out ----------------
__global__ __launch_bounds__(256) void ln_kernel(
    const float* __restrict__ in, float* __restrict__ out,
    const float* __restrict__ g, const float* __restrict__ b,
    int row0, int rstride)
{
    int r = blockIdx.x;
    int tid = threadIdx.x;
    size_t base = (size_t)(row0 + (size_t)r * rstride) * DD;
    float v[4];
    float s1 = 0.f, s2 = 0.f;
#pragma unroll
    for (int i = 0; i < 4; ++i) {
        v[i] = in[base + i * 256 + tid];
        s1 += v[i]; s2 += v[i] * v[i];
    }
    s1 = warp_sum(s1); s2 = warp_sum(s2);
    __shared__ float a1[4], a2[4];
    int w = tid >> 6;
    if ((tid & 63) == 0) { a1[w] = s1; a2[w] = s2; }
    __syncthreads();
    s1 = a1[0] + a1[1] + a1[2] + a1[3];
    s2 = a2[0] + a2[1] + a2[2] + a2[3];
    float mu  = s1 * (1.0f / DD);
    float var = s2 * (1.0f / DD) - mu * mu;
    var = var < 0.f ? 0.f : var;
    float rs = rsqrtf(var + 1e-5f);
#pragma unroll
    for (int i = 0; i < 4; ++i) {
        int c = i * 256 + tid;
        out[(size_t)r * DD + c] = (v[i] - mu) * rs * g[c] + b[c];
    }
}

// ---------------- LayerNorm bf16 out ----------------
__global__ __launch_bounds__(256) void ln_bf16_kernel(
    const float* __restrict__ in, bf16* __restrict__ out,
    const float* __restrict__ g, const float* __restrict__ b)
{
    int r = blockIdx.x;
    int tid = threadIdx.x;
    size_t base = (size_t)r * DD;
    float v[4];
    float s1 = 0.f, s2 = 0.f;
#pragma unroll
    for (int i = 0; i < 4; ++i) {
        v[i] = in[base + i * 256 + tid];
        s1 += v[i]; s2 += v[i] * v[i];
    }
    s1 = warp_sum(s1); s2 = warp_sum(s2);
    __shared__ float a1[4], a2[4];
    int w = tid >> 6;
    if ((tid & 63) == 0) { a1[w] = s1; a2[w] = s2; }
    __syncthreads();
    s1 = a1[0] + a1[1] + a1[2] + a1[3];
    s2 = a2[0] + a2[1] + a2[2] + a2[3];
    float mu  = s1 * (1.0f / DD);
    float var = s2 * (1.0f / DD) - mu * mu;
    var = var < 0.f ? 0.f : var;
    float rs = rsqrtf(var + 1e-5f);
#pragma unroll
    for (int i = 0; i < 4; ++i) {
        int c = i * 256 + tid;
        out[base + c] = __float2bfloat16((v[i] - mu) * rs * g[c] + b[c]);
    }
}

// ---------------- bf16 MFMA GEMM (128x128 tile, BK=32, 4 waves) ----------------
__global__ __launch_bounds__(256) void mfma_gemm_kernel(
    const bf16* __restrict__ A, const bf16* __restrict__ W,
    const float* __restrict__ bias,
    float* __restrict__ outf, bf16* __restrict__ outb,
    int M, int obs, int oro, const float* __restrict__ pe)
{
    __shared__ bf16 As[128 * 32];
    __shared__ bf16 Ws[128 * 32];
    int tid  = threadIdx.x;
    int lane = tid & 63;
    int wave = tid >> 6;
    int m0 = blockIdx.y * 128;
    int n0 = blockIdx.x * 128;
    int wm = (wave >> 1) << 6;     // 0 / 64
    int wn = (wave & 1) << 6;      // 0 / 64

    f32x4 acc[4][4] = {};

    int soff  = wave * 1024 + lane * 16;   // issue-0 byte offset
    int srow  = soff >> 6;                 // row in tile (64B rows)
    int scol  = (soff & 63) >> 1;          // bf16 column
    char* lA0 = (char*)As + wave * 1024;
    char* lA1 = (char*)As + 4096 + wave * 1024;
    char* lW0 = (char*)Ws + wave * 1024;
    char* lW1 = (char*)Ws + 4096 + wave * 1024;

    int fRow = lane & 15;
    int kOff = (lane >> 4) << 3;           // 0,8,16,24

    for (int k0 = 0; k0 < DD; k0 += 32) {
        GLD16(A + (size_t)(m0 + srow) * DD + k0 + scol,      lA0);
        GLD16(A + (size_t)(m0 + 64 + srow) * DD + k0 + scol, lA1);
        GLD16(W + (size_t)(n0 + srow) * DD + k0 + scol,      lW0);
        GLD16(W + (size_t)(n0 + 64 + srow) * DD + k0 + scol, lW1);
        __syncthreads();
        short8 a[4], b[4];
#pragma unroll
        for (int mi = 0; mi < 4; ++mi)
            a[mi] = *(const short8*)(As + (wm + mi * 16 + fRow) * 32 + kOff);
#pragma unroll
        for (int ni = 0; ni < 4; ++ni)
            b[ni] = *(const short8*)(Ws + (wn + ni * 16 + fRow) * 32 + kOff);
#pragma unroll
        for (int mi = 0; mi < 4; ++mi)
#pragma unroll
            for (int ni = 0; ni < 4; ++ni)
                acc[mi][ni] = __builtin_amdgcn_mfma_f32_16x16x32_bf16(
                    a[mi], b[ni], acc[mi][ni], 0, 0, 0);
        __syncthreads();
    }

    int cCol  = lane & 15;
    int cRow4 = (lane >> 4) << 2;
#pragma unroll
    for (int mi = 0; mi < 4; ++mi) {
#pragma unroll
        for (int ni = 0; ni < 4; ++ni) {
#pragma unroll
            for (int r = 0; r < 4; ++r) {
                int row = m0 + wm + mi * 16 + cRow4 + r;
                int col = n0 + wn + ni * 16 + cCol;
                if (row < M) {
                    float v = acc[mi][ni][r] + bias[col];
                    if (outf) {
                        v += pe[(size_t)(row & 1023) * DD + col];
                        int orow = (row >> 10) * obs + oro + (row & 1023);
                        outf[(size_t)orow * DD + col] = v;
                    } else {
                        outb[(size_t)row * DD + col] = __float2bfloat16(v);
                    }
                }
            }
        }
    }
}

// ---------------- small GEMM (M<=16): one wave per output column ----------------
template<int M>
__global__ __launch_bounds__(256) void small_gemm_kernel(
    const float* __restrict__ A, const float* __restrict__ W,
    const float* __restrict__ bias, float* __restrict__ out,
    const float* __restrict__ res, int gelu)
{
    __shared__ float As[M * DD];
    int tid = threadIdx.x;
#pragma unroll
    for (int i = 0; i < M; ++i) {
        int idx = (i * 256 + tid) * 4;
        *(float4*)(As + idx) = *(const float4*)(A + idx);
    }
    __syncthreads();
    int lane = tid & 63;
    int w = tid >> 6;
    int n = blockIdx.x * 4 + w;
    const float* Wr = W + (size_t)n * DD;
    float acc[M] = {};
#pragma unroll
    for (int j = 0; j < 4; ++j) {
        float4 wv = *(const float4*)(Wr + j * 256 + lane * 4);
#pragma unroll
        for (int m = 0; m < M; ++m) {
            float4 av = *(const float4*)(As + m * DD + j * 256 + lane * 4);
            acc[m] += av.x * wv.x + av.y * wv.y + av.z * wv.z + av.w * wv.w;
        }
    }
#pragma unroll
    for (int m = 0; m < M; ++m) acc[m] = warp_sum(acc[m]);
    if (lane == 0) {
#pragma unroll
        for (int m = 0; m < M; ++m) {
            float v = acc[m] + bias[n];
            if (gelu) v = 0.5f * v * (1.0f + erff(v * 0.70710678118654752f));
            if (res)  v += res[(size_t)m * DD + n];
            out[(size_t)m * DD + n] = v;
        }
    }
}

// ---------------- split-K flash-decode attention: partial kernel ----------------
// grid: 64 bh * NCH chunks; block 256. Chunk c covers keys [c*CHS, (c+1)*CHS).
// Writes per (bh,qi,chunk): pm (max), pl (sum-exp), pacc[64] (exp-weighted V).
template<int LQ>
__global__ __launch_bounds__(256) void attn_part_kernel(
    const float* __restrict__ qh, const bf16* __restrict__ kh,
    const bf16* __restrict__ vh, float* __restrict__ pm,
    float* __restrict__ pl, float* __restrict__ pacc)
{
    int blk = blockIdx.x;
    int c  = blk & (NCH - 1);
    int bh = blk >> 2;
    int b = bh >> 4, h = bh & 15;
    int tid = threadIdx.x;
    int lane = tid & 63, w = tid >> 6;

    __shared__ float qs[LQ][64];
    __shared__ float sc[LQ][CHS];
    __shared__ float redm[4][LQ];
    __shared__ float redl[4][LQ];
    __shared__ float paccs[4][LQ][64];

    if (w < LQ) qs[w][lane] = qh[(size_t)(b * LQ + w) * DD + h * 64 + lane];
    __syncthreads();

    int kbeg = c * CHS;
    // scores: one key per thread (thread 0 also takes key 256 of the chunk)
    for (int t = tid; t < CHS; t += 256) {
        const ushort4* kr = (const ushort4*)((const unsigned short*)kh
            + (size_t)(b * LKV + kbeg + t) * DD + h * 64);
        float kf[64];
#pragma unroll
        for (int i = 0; i < 16; ++i) {
            ushort4 kk = kr[i];
            kf[i*4+0] = b2f(kk.x); kf[i*4+1] = b2f(kk.y);
            kf[i*4+2] = b2f(kk.z); kf[i*4+3] = b2f(kk.w);
        }
#pragma unroll
        for (int qi = 0; qi < LQ; ++qi) {
            float s = 0.f;
#pragma unroll
            for (int d = 0; d < 64; ++d) s += qs[qi][d] * kf[d];
            sc[qi][t] = s * 0.125f;
        }
    }
    __syncthreads();

    float M[LQ], L[LQ];
#pragma unroll
    for (int qi = 0; qi < LQ; ++qi) {
        float lm = -1e30f;
        for (int t = tid; t < CHS; t += 256) lm = fmaxf(lm, sc[qi][t]);
#pragma unroll
        for (int o = 32; o > 0; o >>= 1) lm = fmaxf(lm, __shfl_xor(lm, o));
        if (lane == 0) redm[w][qi] = lm;
    }
    __syncthreads();
#pragma unroll
    for (int qi = 0; qi < LQ; ++qi)
        M[qi] = fmaxf(fmaxf(redm[0][qi], redm[1][qi]), fmaxf(redm[2][qi], redm[3][qi]));

#pragma unroll
    for (int qi = 0; qi < LQ; ++qi) {
        float ls = 0.f;
        for (int t = tid; t < CHS; t += 256) {
            float e = expf(sc[qi][t] - M[qi]);
            sc[qi][t] = e;
            ls += e;
        }
        ls = warp_sum(ls);
        if (lane == 0) redl[w][qi] = ls;
    }
    __syncthreads();
#pragma unroll
    for (int qi = 0; qi < LQ; ++qi)
        L[qi] = redl[0][qi] + redl[1][qi] + redl[2][qi] + redl[3][qi];

    // PV: lane = dim, wave w covers keys [w*65, min(CHS, w*65+65))
    {
        int k0 = w * 65;
        int k1 = (k0 + 65 < CHS) ? k0 + 65 : CHS;
        float acc[LQ] = {};
        const unsigned short* vb = (const unsigned short*)vh
            + (size_t)(b * LKV + kbeg) * DD + h * 64 + lane;
        for (int k = k0; k < k1; ++k) {
            float v = b2f(vb[(size_t)k * DD]);
#pragma unroll
            for (int qi = 0; qi < LQ; ++qi) acc[qi] += sc[qi][k] * v;
        }
#pragma unroll
        for (int qi = 0; qi < LQ; ++qi) paccs[w][qi][lane] = acc[qi];
    }
    __syncthreads();
    if (tid < 64) {
#pragma unroll
        for (int qi = 0; qi < LQ; ++qi) {
            float s = paccs[0][qi][tid] + paccs[1][qi][tid]
                    + paccs[2][qi][tid] + paccs[3][qi][tid];
            pacc[(size_t)((bh * 4 + qi) * NCH + c) * 64 + tid] = s;
        }
    }
    if (tid < LQ) {
        pm[(bh * 4 + tid) * NCH + c] = M[tid];
        pl[(bh * 4 + tid) * NCH + c] = L[tid];
    }
}

// ---------------- split-K attention: combine kernel ----------------
template<int LQ>
__global__ __launch_bounds__(256) void attn_comb_kernel(
    const float* __restrict__ pm, const float* __restrict__ pl,
    const float* __restrict__ pacc, float* __restrict__ out)
{
    int bh = blockIdx.x;
    int b = bh >> 4, h = bh & 15;
    int tid = threadIdx.x;
    int qi = tid >> 6, d = tid & 63;
    if (qi >= LQ) return;
    int base = (bh * 4 + qi) * NCH;
    float m0 = pm[base], m1 = pm[base+1], m2 = pm[base+2], m3 = pm[base+3];
    float M = fmaxf(fmaxf(m0, m1), fmaxf(m2, m3));
    float w0 = expf(m0 - M), w1 = expf(m1 - M), w2 = expf(m2 - M), w3 = expf(m3 - M);
    float L = pl[base]*w0 + pl[base+1]*w1 + pl[base+2]*w2 + pl[base+3]*w3;
    float A = pacc[(size_t)(base+0)*64 + d]*w0 + pacc[(size_t)(base+1)*64 + d]*w1
            + pacc[(size_t)(base+2)*64 + d]*w2 + pacc[(size_t)(base+3)*64 + d]*w3;
    out[(size_t)(b * LQ + qi) * DD + h * 64 + d] = A / L;
}

// ---------------- small copies ----------------
__global__ __launch_bounds__(256) void copy_state_kernel(
    const float* __restrict__ sf, float* __restrict__ cat)
{
    int r = blockIdx.x;
    int b = r >> 2, s = r & 3;
    int tid = threadIdx.x;
#pragma unroll
    for (int i = 0; i < 4; ++i)
        cat[(size_t)(b * LKV + s) * DD + i * 256 + tid] = sf[(size_t)r * DD + i * 256 + tid];
}

__global__ __launch_bounds__(256) void copy_lolast_kernel(
    const float* __restrict__ cat, float* __restrict__ dst)
{
    int b = blockIdx.x;
    int tid = threadIdx.x;
#pragma unroll
    for (int i = 0; i < 4; ++i)
        dst[(size_t)b * DD + i * 256 + tid] =
            cat[(size_t)(b * LKV + (TT - 1)) * DD + i * 256 + tid];
}

// ---------------- slot logits ----------------
__global__ __launch_bounds__(256) void logits_kernel(
    const float* __restrict__ ln, const float* __restrict__ ctx, float* __restrict__ out)
{
    int r = blockIdx.x;
    int tid = threadIdx.x;
    float s = 0.f;
    for (int i = tid; i < DD; i += 256) s += ln[(size_t)r * DD + i] * ctx[i];
    s = warp_sum(s);
    __shared__ float a[4];
    if ((tid & 63) == 0) a[tid >> 6] = s;
    __syncthreads();
    if (tid == 0) out[r] = a[0] + a[1] + a[2] + a[3];
}

// ---------------- top-2 gate + state update ----------------
__global__ __launch_bounds__(256) void gate_kernel(
    const float* __restrict__ logits, const float* __restrict__ state_old,
    const float* __restrict__ lat2, float* __restrict__ cat_o,
    float* __restrict__ dout)
{
    int b = blockIdx.x;
    int tid = threadIdx.x;
    __shared__ float alpha[NS];
    if (tid == 0) {
        float l[NS];
        for (int s = 0; s < NS; ++s) l[s] = logits[b * NS + s];
        int i0 = 0;
        for (int s = 1; s < NS; ++s) if (l[s] > l[i0]) i0 = s;
        int i1 = (i0 == 0) ? 1 : 0;
        for (int s = 0; s < NS; ++s) if (s != i0 && l[s] > l[i1]) i1 = s;
        float mx = fmaxf(l[i0], l[i1]);
        float e0 = expf(l[i0] - mx), e1 = expf(l[i1] - mx);
        float inv = 1.f / (e0 + e1);
        for (int s = 0; s < NS; ++s) alpha[s] = 0.f;
        alpha[i0] = e0 * inv;
        alpha[i1] += e1 * inv;
        dout[4096 + b * 2 + 0] = (float)i0;
        dout[4096 + b * 2 + 1] = (float)i1;
    }
    __syncthreads();
    for (int idx = tid; idx < NS * DD; idx += 256) {
        int s = idx >> 10;
        int d = idx & 1023;
        float so = state_old[(size_t)b * NS * DD + idx];
        float lt = lat2[(size_t)b * NS * DD + idx];
        float ns = 0.6f * so + 0.4f * alpha[s] * tanhf(lt);
        cat_o[(size_t)(b * LKV + TT + s) * DD + d] = ns;
        dout[4104 + b * NS * DD + idx] = ns;
    }
}

extern "C" void kernel_launch(void* const* d_in, const int* in_sizes, int n_in,
                              void* d_out, int out_size, void* d_ws, size_t ws_size,
                              hipStream_t stream)
{
    const float* x        = (const float*)d_in[0];
    const float* state0   = (const float*)d_in[1];
    const float* se_W     = (const float*)d_in[2];
    const float* se_b     = (const float*)d_in[3];
    const float* s_Wq     = (const float*)d_in[4];
    const float* s_bq     = (const float*)d_in[5];
    const float* s_Wk     = (const float*)d_in[6];
    const float* s_bk     = (const float*)d_in[7];
    const float* s_Wv     = (const float*)d_in[8];
    const float* s_bv     = (const float*)d_in[9];
    const float* s_Wo     = (const float*)d_in[10];
    const float* s_bo     = (const float*)d_in[11];
    const float* s_lnq_g  = (const float*)d_in[12];
    const float* s_lnq_b  = (const float*)d_in[13];
    const float* s_lnkv_g = (const float*)d_in[14];
    const float* s_lnkv_b = (const float*)d_in[15];
    const float* s_fc1_W  = (const float*)d_in[16];
    const float* s_fc1_b  = (const float*)d_in[17];
    const float* s_fc2_W  = (const float*)d_in[18];
    const float* s_fc2_b  = (const float*)d_in[19];
    const float* s_lnffn_g= (const float*)d_in[20];
    const float* s_lnffn_b= (const float*)d_in[21];
    const float* s_lnslot_g=(const float*)d_in[22];
    const float* s_lnslot_b=(const float*)d_in[23];
    const float* slot_ctx = (const float*)d_in[24];
    const float* oe_W     = (const float*)d_in[25];
    const float* oe_b     = (const float*)d_in[26];
    const float* o_Wq     = (const float*)d_in[27];
    const float* o_bq     = (const float*)d_in[28];
    const float* o_Wk     = (const float*)d_in[29];
    const float* o_bk     = (const float*)d_in[30];
    const float* o_Wv     = (const float*)d_in[31];
    const float* o_bv     = (const float*)d_in[32];
    const float* o_Wo     = (const float*)d_in[33];
    const float* o_bo     = (const float*)d_in[34];
    const float* o_lnq_g  = (const float*)d_in[35];
    const float* o_lnq_b  = (const float*)d_in[36];
    const float* o_lnkv_g = (const float*)d_in[37];
    const float* o_lnkv_b = (const float*)d_in[38];
    const float* o_fc1_W  = (const float*)d_in[39];
    const float* o_fc1_b  = (const float*)d_in[40];
    const float* o_fc2_W  = (const float*)d_in[41];
    const float* o_fc2_b  = (const float*)d_in[42];
    const float* o_lnffn_g= (const float*)d_in[43];
    const float* o_lnffn_b= (const float*)d_in[44];
    const float* op_W     = (const float*)d_in[45];
    const float* op_b     = (const float*)d_in[46];

    float* ws  = (float*)d_ws;
    float* pe   = ws;                        // 1,048,576 f32
    float* cat  = ws + 1048576;              // 4,210,688 f32
    bf16*  lnbb = (bf16*)(ws + 5259264);     // 4224*1024 bf16
    bf16*  kh   = (bf16*)(ws + 7421952);     // 4112*1024 bf16
    bf16*  vh   = (bf16*)(ws + 9527296);
    bf16*  xb   = (bf16*)(ws + 11632640);    // 4096*1024 bf16
    bf16*  wb   = (bf16*)(ws + 13729792);    // 6 x 1M bf16
    bf16*  seWb = wb;
    bf16*  oeWb = wb + 1048576;
    bf16*  sWkb = wb + 2097152;
    bf16*  sWvb = wb + 3145728;
    bf16*  oWkb = wb + 4194304;
    bf16*  oWvb = wb + 5242880;
    float* sm   = ws + 16875520;
    float* q_s    = sm;
    float* qh_s   = sm + 16384;
    float* attn_s = sm + 32768;
    float* lat1   = sm + 49152;
    float* hffn   = sm + 65536;
    float* g1     = sm + 81920;
    float* lat2   = sm + 98304;
    float* lnslot = sm + 114688;
    float* logitsb= sm + 131072;
    float* q2     = sm + 131136;
    float* q2h    = q2 + 4096;
    float* attn2  = q2h + 4096;
    float* lo_last= attn2 + 4096;
    float* lo1    = lo_last + 4096;
    float* h2     = lo1 + 4096;
    float* g2     = h2 + 4096;
    float* lo2    = g2 + 4096;
    float* pmb    = lo2 + 4096;    // 1024
    float* plb    = pmb + 1024;    // 1024
    float* paccb  = plb + 1024;    // 65536
    float* out = (float*)d_out;

    dim3 blk(256);
    dim3 gBig(8, 32);    // N=1024, M=4096
    dim3 gBigP(8, 33);   // M=4112 padded
    dim3 gSm(256);

    // ---- conversions + PE ----
    cvt_kernel<<<4096, blk, 0, stream>>>(x, xb);
    cvt_kernel<<<1024, blk, 0, stream>>>(se_W, seWb);
    cvt_kernel<<<1024, blk, 0, stream>>>(oe_W, oeWb);
    cvt_kernel<<<1024, blk, 0, stream>>>(s_Wk, sWkb);
    cvt_kernel<<<1024, blk, 0, stream>>>(s_Wv, sWvb);
    cvt_kernel<<<1024, blk, 0, stream>>>(o_Wk, oWkb);
    cvt_kernel<<<1024, blk, 0, stream>>>(o_Wv, oWvb);
    pe_kernel<<<TT, blk, 0, stream>>>(pe);

    // ---- state branch ----
    copy_state_kernel<<<16, blk, 0, stream>>>(state0, cat);
    mfma_gemm_kernel<<<gBig, blk, 0, stream>>>(xb, seWb, se_b, cat, nullptr,
        4096, LKV, NS, pe);                                            // lx -> cat rows b*1028+4+t
    ln_kernel<<<16, blk, 0, stream>>>(state0, q_s, s_lnq_g, s_lnq_b, 0, 1);
    ln_bf16_kernel<<<4112, blk, 0, stream>>>(cat, lnbb, s_lnkv_g, s_lnkv_b);
    small_gemm_kernel<16><<<gSm, blk, 0, stream>>>(q_s, s_Wq, s_bq, qh_s, nullptr, 0);
    mfma_gemm_kernel<<<gBigP, blk, 0, stream>>>(lnbb, sWkb, s_bk, nullptr, kh,
        4112, 0, 0, nullptr);
    mfma_gemm_kernel<<<gBigP, blk, 0, stream>>>(lnbb, sWvb, s_bv, nullptr, vh,
        4112, 0, 0, nullptr);
    attn_part_kernel<4><<<256, blk, 0, stream>>>(qh_s, kh, vh, pmb, plb, paccb);
    attn_comb_kernel<4><<<64, blk, 0, stream>>>(pmb, plb, paccb, attn_s);
    small_gemm_kernel<16><<<gSm, blk, 0, stream>>>(attn_s, s_Wo, s_bo, lat1, state0, 0);
    ln_kernel<<<16, blk, 0, stream>>>(lat1, hffn, s_lnffn_g, s_lnffn_b, 0, 1);
    small_gemm_kernel<16><<<gSm, blk, 0, stream>>>(hffn, s_fc1_W, s_fc1_b, g1, nullptr, 1);
    small_gemm_kernel<16><<<gSm, blk, 0, stream>>>(g1, s_fc2_W, s_fc2_b, lat2, lat1, 0);
    ln_kernel<<<16, blk, 0, stream>>>(lat2, lnslot, s_lnslot_g, s_lnslot_b, 0, 1);
    logits_kernel<<<16, blk, 0, stream>>>(lnslot, slot_ctx, logitsb);
    gate_kernel<<<NB, blk, 0, stream>>>(logitsb, state0, lat2, cat, out);

    // ---- out branch ----
    mfma_gemm_kernel<<<gBig, blk, 0, stream>>>(xb, oeWb, oe_b, cat, nullptr,
        4096, LKV, 0, pe);                                             // lo -> cat rows b*1028+t
    ln_kernel<<<NB, blk, 0, stream>>>(cat, q2, o_lnq_g, o_lnq_b, TT - 1, LKV);
    ln_bf16_kernel<<<4112, blk, 0, stream>>>(cat, lnbb, o_lnkv_g, o_lnkv_b);
    small_gemm_kernel<4><<<gSm, blk, 0, stream>>>(q2, o_Wq, o_bq, q2h, nullptr, 0);
    mfma_gemm_kernel<<<gBigP, blk, 0, stream>>>(lnbb, oWkb, o_bk, nullptr, kh,
        4112, 0, 0, nullptr);
    mfma_gemm_kernel<<<gBigP, blk, 0, stream>>>(lnbb, oWvb, o_bv, nullptr, vh,
        4112, 0, 0, nullptr);
    attn_part_kernel<1><<<256, blk, 0, stream>>>(q2h, kh, vh, pmb, plb, paccb);
    attn_comb_kernel<1><<<64, blk, 0, stream>>>(pmb, plb, paccb, attn2);
    copy_lolast_kernel<<<NB, blk, 0, stream>>>(cat, lo_last);
    small_gemm_kernel<4><<<gSm, blk, 0, stream>>>(attn2, o_Wo, o_bo, lo1, lo_last, 0);
    ln_kernel<<<NB, blk, 0, stream>>>(lo1, h2, o_lnffn_g, o_lnffn_b, 0, 1);
    small_gemm_kernel<4><<<gSm, blk, 0, stream>>>(h2, o_fc1_W, o_fc1_b, g2, nullptr, 1);
    small_gemm_kernel<4><<<gSm, blk, 0, stream>>>(g2, o_fc2_W, o_fc2_b, lo2, lo1, 0);
    small_gemm_kernel<4><<<gSm, blk, 0, stream>>>(lo2, op_W, op_b, out, nullptr, 0);
}

// Round 6
// 285.244 us; speedup vs baseline: 9.7291x; 1.3719x over previous
//
#include <hip/hip_runtime.h>
#include <hip/hip_bf16.h>

#define DD 1024
#define NB 4
#define TT 1024
#define NH 16
#define NS 4
#define LKV 1028   // NS + TT
#define NCH 4
#define CHS 257    // keys per chunk (4*257 = 1028)

typedef __hip_bfloat16 bf16;
typedef __attribute__((ext_vector_type(8))) short short8;
typedef __attribute__((ext_vector_type(4))) float f32x4;

#define GLD16(gp, lp) __builtin_amdgcn_global_load_lds( \
    (const __attribute__((address_space(1))) unsigned int*)(const void*)(gp), \
    (__attribute__((address_space(3))) unsigned int*)(void*)(lp), 16, 0, 0)

__device__ __forceinline__ float warp_sum(float v) {
#pragma unroll
    for (int o = 32; o > 0; o >>= 1) v += __shfl_xor(v, o);
    return v;
}

__device__ __forceinline__ float b2f(unsigned short u) {
    union { unsigned int i; float f; } x; x.i = ((unsigned)u) << 16; return x.f;
}

// ================= prep: cvt x + 6 weights, PE table, state-row copy ==========
struct PrepArgs {
    const float* cin[7];   // x, seW, oeW, sWk, sWv, oWk, oWv
    bf16* cout[7];
    const float* state0;
    float* cat;
    float* pe;
};

__global__ __launch_bounds__(256) void prep_kernel(PrepArgs a) {
    int bid = blockIdx.x;
    int tid = threadIdx.x;
    if (bid < 10240) {
        const float* in; bf16* out; size_t off;
        if (bid < 4096) { in = a.cin[0]; out = a.cout[0]; off = (size_t)bid * 1024; }
        else {
            int w = (bid - 4096) >> 10;
            in = a.cin[1 + w]; out = a.cout[1 + w];
            off = (size_t)((bid - 4096) & 1023) * 1024;
        }
        size_t i = off + tid * 4;
        float4 v = *(const float4*)(in + i);
        out[i + 0] = __float2bfloat16(v.x);
        out[i + 1] = __float2bfloat16(v.y);
        out[i + 2] = __float2bfloat16(v.z);
        out[i + 3] = __float2bfloat16(v.w);
    } else if (bid < 11264) {
        int t = bid - 10240;
#pragma unroll
        for (int i = 0; i < 2; ++i) {
            int j = i * 256 + tid;                       // 0..511
            float ang = (float)t * exp2f(-(float)j * (1.0f / 256.0f));
            a.pe[(size_t)t * DD + j]       = sinf(ang);
            a.pe[(size_t)t * DD + 512 + j] = cosf(ang);
        }
    } else {
        int r = bid - 11264;       // 0..15
        int b = r >> 2, s = r & 3;
#pragma unroll
        for (int i = 0; i < 4; ++i)
            a.cat[(size_t)(b * LKV + s) * DD + i * 256 + tid] =
                a.state0[(size_t)r * DD + i * 256 + tid];
    }
}

// ================= LayerNorm f32 out (generic rows) ==========================
__global__ __launch_bounds__(256) void ln_kernel(
    const float* __restrict__ in, float* __restrict__ out,
    const float* __restrict__ g, const float* __restrict__ b,
    int row0, int rstride)
{
    int r = blockIdx.x;
    int tid = threadIdx.x;
    size_t base = (size_t)(row0 + (size_t)r * rstride) * DD;
    float v[4];
    float s1 = 0.f, s2 = 0.f;
#pragma unroll
    for (int i = 0; i < 4; ++i) {
        v[i] = in[base + i * 256 + tid];
        s1 += v[i]; s2 += v[i] * v[i];
    }
    s1 = warp_sum(s1); s2 = warp_sum(s2);
    __shared__ float a1[4], a2[4];
    int w = tid >> 6;
    if ((tid & 63) == 0) { a1[w] = s1; a2[w] = s2; }
    __syncthreads();
    s1 = a1[0] + a1[1] + a1[2] + a1[3];
    s2 = a2[0] + a2[1] + a2[2] + a2[3];
    float mu  = s1 * (1.0f / DD);
    float var = s2 * (1.0f / DD) - mu * mu;
    var = var < 0.f ? 0.f : var;
    float rs = rsqrtf(var + 1e-5f);
#pragma unroll
    for (int i = 0; i < 4; ++i) {
        int c = i * 256 + tid;
        out[(size_t)r * DD + c] = (v[i] - mu) * rs * g[c] + b[c];
    }
}

// ================= fused LayerNorm -> bf16 (state-kv rows + out token rows) ===
__global__ __launch_bounds__(256) void ln_fused_kernel(
    const float* __restrict__ cat, const float* __restrict__ cat2,
    bf16* __restrict__ lnbb, bf16* __restrict__ lnbb2,
    const float* __restrict__ sg, const float* __restrict__ sb,
    const float* __restrict__ og, const float* __restrict__ ob)
{
    int bid = blockIdx.x;
    int tid = threadIdx.x;
    const float* in; bf16* out; const float* g; const float* b;
    if (bid < 4112) {
        in = cat + (size_t)bid * DD; out = lnbb + (size_t)bid * DD; g = sg; b = sb;
    } else {
        int r = bid - 4112;
        int row = (r >> 10) * LKV + (r & 1023);
        in = cat2 + (size_t)row * DD; out = lnbb2 + (size_t)r * DD; g = og; b = ob;
    }
    float v[4];
    float s1 = 0.f, s2 = 0.f;
#pragma unroll
    for (int i = 0; i < 4; ++i) {
        v[i] = in[i * 256 + tid];
        s1 += v[i]; s2 += v[i] * v[i];
    }
    s1 = warp_sum(s1); s2 = warp_sum(s2);
    __shared__ float a1[4], a2[4];
    int w = tid >> 6;
    if ((tid & 63) == 0) { a1[w] = s1; a2[w] = s2; }
    __syncthreads();
    s1 = a1[0] + a1[1] + a1[2] + a1[3];
    s2 = a2[0] + a2[1] + a2[2] + a2[3];
    float mu  = s1 * (1.0f / DD);
    float var = s2 * (1.0f / DD) - mu * mu;
    var = var < 0.f ? 0.f : var;
    float rs = rsqrtf(var + 1e-5f);
#pragma unroll
    for (int i = 0; i < 4; ++i) {
        int c = i * 256 + tid;
        out[c] = __float2bfloat16((v[i] - mu) * rs * g[c] + b[c]);
    }
}

// ================= MFMA tile body (128x128, BK=32, 4 waves) ===================
__device__ __forceinline__ void mfma_tile(
    const bf16* __restrict__ A, const bf16* __restrict__ W,
    const float* __restrict__ bias,
    float* __restrict__ outf, bf16* __restrict__ outb,
    int M, int obs, int oro, const float* __restrict__ pe,
    bf16* As, bf16* Ws)
{
    int tid  = threadIdx.x;
    int lane = tid & 63;
    int wave = tid >> 6;
    int m0 = blockIdx.y * 128;
    int n0 = blockIdx.x * 128;
    int wm = (wave >> 1) << 6;
    int wn = (wave & 1) << 6;

    f32x4 acc[4][4] = {};

    int soff  = wave * 1024 + lane * 16;
    int srow  = soff >> 6;
    int scol  = (soff & 63) >> 1;
    char* lA0 = (char*)As + wave * 1024;
    char* lA1 = (char*)As + 4096 + wave * 1024;
    char* lW0 = (char*)Ws + wave * 1024;
    char* lW1 = (char*)Ws + 4096 + wave * 1024;

    int fRow = lane & 15;
    int kOff = (lane >> 4) << 3;

    for (int k0 = 0; k0 < DD; k0 += 32) {
        GLD16(A + (size_t)(m0 + srow) * DD + k0 + scol,      lA0);
        GLD16(A + (size_t)(m0 + 64 + srow) * DD + k0 + scol, lA1);
        GLD16(W + (size_t)(n0 + srow) * DD + k0 + scol,      lW0);
        GLD16(W + (size_t)(n0 + 64 + srow) * DD + k0 + scol, lW1);
        __syncthreads();
        short8 a[4], b[4];
#pragma unroll
        for (int mi = 0; mi < 4; ++mi)
            a[mi] = *(const short8*)(As + (wm + mi * 16 + fRow) * 32 + kOff);
#pragma unroll
        for (int ni = 0; ni < 4; ++ni)
            b[ni] = *(const short8*)(Ws + (wn + ni * 16 + fRow) * 32 + kOff);
#pragma unroll
        for (int mi = 0; mi < 4; ++mi)
#pragma unroll
            for (int ni = 0; ni < 4; ++ni)
                acc[mi][ni] = __builtin_amdgcn_mfma_f32_16x16x32_bf16(
                    a[mi], b[ni], acc[mi][ni], 0, 0, 0);
        __syncthreads();
    }

    int cCol  = lane & 15;
    int cRow4 = (lane >> 4) << 2;
#pragma unroll
    for (int mi = 0; mi < 4; ++mi) {
#pragma unroll
        for (int ni = 0; ni < 4; ++ni) {
#pragma unroll
            for (int r = 0; r < 4; ++r) {
                int row = m0 + wm + mi * 16 + cRow4 + r;
                int col = n0 + wn + ni * 16 + cCol;
                if (row < M) {
                    float v = acc[mi][ni][r] + bias[col];
                    if (outf) {
                        v += pe[(size_t)(row & 1023) * DD + col];
                        int orow = (row >> 10) * obs + oro + (row & 1023);
                        outf[(size_t)orow * DD + col] = v;
                    } else {
                        int orow = obs ? ((row >> 10) * obs + (row & 1023)) : row;
                        outb[(size_t)orow * DD + col] = __float2bfloat16(v);
                    }
                }
            }
        }
    }
}

// ================= fused embeds: z=0 state (se), z=1 out (oe) =================
__global__ __launch_bounds__(256) void embed_fused_kernel(
    const bf16* __restrict__ xb,
    const bf16* __restrict__ seW, const bf16* __restrict__ oeW,
    const float* __restrict__ seb, const float* __restrict__ oeb,
    float* __restrict__ cat, float* __restrict__ cat2,
    const float* __restrict__ pe)
{
    __shared__ bf16 As[128 * 32];
    __shared__ bf16 Ws[128 * 32];
    int z = blockIdx.z;
    const bf16* W = z ? oeW : seW;
    const float* bias = z ? oeb : seb;
    float* outf = z ? cat2 : cat;
    int oro = z ? 0 : NS;
    mfma_tile(xb, W, bias, outf, nullptr, 4096, LKV, oro, pe, As, Ws);
}

// ================= fused K/V GEMMs: z0/z1 state branch, z2/z3 out tokens ======
__global__ __launch_bounds__(256) void kv_fused_kernel(
    const bf16* __restrict__ lnbb, const bf16* __restrict__ lnbb2,
    const bf16* __restrict__ W0, const bf16* __restrict__ W1,
    const bf16* __restrict__ W2, const bf16* __restrict__ W3,
    const float* __restrict__ b0, const float* __restrict__ b1,
    const float* __restrict__ b2, const float* __restrict__ b3,
    bf16* __restrict__ o0, bf16* __restrict__ o1,
    bf16* __restrict__ o2, bf16* __restrict__ o3)
{
    __shared__ bf16 As[128 * 32];
    __shared__ bf16 Ws[128 * 32];
    int z = blockIdx.z;
    const bf16* Warr[4] = {W0, W1, W2, W3};
    const float* barr[4] = {b0, b1, b2, b3};
    bf16* oarr[4] = {o0, o1, o2, o3};
    const bf16* A = (z < 2) ? lnbb : lnbb2;
    int M   = (z < 2) ? 4112 : 4096;
    int obs = (z < 2) ? 0 : LKV;
    mfma_tile(A, Warr[z], barr[z], nullptr, oarr[z], M, obs, 0, nullptr, As, Ws);
}

// ================= small GEMM (M<=16): one wave per output column =============
// outb != null: bf16 out; remap -> orow = (m>>2)*1028 + 1024 + (m&3)
template<int M>
__global__ __launch_bounds__(256) void small_gemm_kernel(
    const float* __restrict__ A, const float* __restrict__ W,
    const float* __restrict__ bias, float* __restrict__ outf,
    bf16* __restrict__ outb, int remap,
    const float* __restrict__ res, int gelu)
{
    __shared__ float As[M * DD];
    int tid = threadIdx.x;
#pragma unroll
    for (int i = 0; i < M; ++i) {
        int idx = (i * 256 + tid) * 4;
        *(float4*)(As + idx) = *(const float4*)(A + idx);
    }
    __syncthreads();
    int lane = tid & 63;
    int w = tid >> 6;
    int n = blockIdx.x * 4 + w;
    const float* Wr = W + (size_t)n * DD;
    float acc[M] = {};
#pragma unroll
    for (int j = 0; j < 4; ++j) {
        float4 wv = *(const float4*)(Wr + j * 256 + lane * 4);
#pragma unroll
        for (int m = 0; m < M; ++m) {
            float4 av = *(const float4*)(As + m * DD + j * 256 + lane * 4);
            acc[m] += av.x * wv.x + av.y * wv.y + av.z * wv.z + av.w * wv.w;
        }
    }
#pragma unroll
    for (int m = 0; m < M; ++m) acc[m] = warp_sum(acc[m]);
    if (lane == 0) {
#pragma unroll
        for (int m = 0; m < M; ++m) {
            float v = acc[m] + bias[n];
            if (gelu) v = 0.5f * v * (1.0f + erff(v * 0.70710678118654752f));
            if (res)  v += res[(size_t)m * DD + n];
            if (outb) {
                int orow = remap ? ((m >> 2) * LKV + TT + (m & 3)) : m;
                outb[(size_t)orow * DD + n] = __float2bfloat16(v);
            } else {
                outf[(size_t)m * DD + n] = v;
            }
        }
    }
}

// ================= split-K flash-decode attention =============================
template<int LQ>
__global__ __launch_bounds__(256) void attn_part_kernel(
    const float* __restrict__ qh, const bf16* __restrict__ kh,
    const bf16* __restrict__ vh, float* __restrict__ pm,
    float* __restrict__ pl, float* __restrict__ pacc)
{
    int blk = blockIdx.x;
    int c  = blk & (NCH - 1);
    int bh = blk >> 2;
    int b = bh >> 4, h = bh & 15;
    int tid = threadIdx.x;
    int lane = tid & 63, w = tid >> 6;

    __shared__ float qs[LQ][64];
    __shared__ float sc[LQ][CHS];
    __shared__ float redm[4][LQ];
    __shared__ float redl[4][LQ];
    __shared__ float paccs[4][LQ][64];

    if (w < LQ) qs[w][lane] = qh[(size_t)(b * LQ + w) * DD + h * 64 + lane];
    __syncthreads();

    int kbeg = c * CHS;
    for (int t = tid; t < CHS; t += 256) {
        const ushort4* kr = (const ushort4*)((const unsigned short*)kh
            + (size_t)(b * LKV + kbeg + t) * DD + h * 64);
        float kf[64];
#pragma unroll
        for (int i = 0; i < 16; ++i) {
            ushort4 kk = kr[i];
            kf[i*4+0] = b2f(kk.x); kf[i*4+1] = b2f(kk.y);
            kf[i*4+2] = b2f(kk.z); kf[i*4+3] = b2f(kk.w);
        }
#pragma unroll
        for (int qi = 0; qi < LQ; ++qi) {
            float s = 0.f;
#pragma unroll
            for (int d = 0; d < 64; ++d) s += qs[qi][d] * kf[d];
            sc[qi][t] = s * 0.125f;
        }
    }
    __syncthreads();

    float M[LQ], L[LQ];
#pragma unroll
    for (int qi = 0; qi < LQ; ++qi) {
        float lm = -1e30f;
        for (int t = tid; t < CHS; t += 256) lm = fmaxf(lm, sc[qi][t]);
#pragma unroll
        for (int o = 32; o > 0; o >>= 1) lm = fmaxf(lm, __shfl_xor(lm, o));
        if (lane == 0) redm[w][qi] = lm;
    }
    __syncthreads();
#pragma unroll
    for (int qi = 0; qi < LQ; ++qi)
        M[qi] = fmaxf(fmaxf(redm[0][qi], redm[1][qi]), fmaxf(redm[2][qi], redm[3][qi]));

#pragma unroll
    for (int qi = 0; qi < LQ; ++qi) {
        float ls = 0.f;
        for (int t = tid; t < CHS; t += 256) {
            float e = expf(sc[qi][t] - M[qi]);
            sc[qi][t] = e;
            ls += e;
        }
        ls = warp_sum(ls);
        if (lane == 0) redl[w][qi] = ls;
    }
    __syncthreads();
#pragma unroll
    for (int qi = 0; qi < LQ; ++qi)
        L[qi] = redl[0][qi] + redl[1][qi] + redl[2][qi] + redl[3][qi];

    {
        int k0 = w * 65;
        int k1 = (k0 + 65 < CHS) ? k0 + 65 : CHS;
        float acc[LQ] = {};
        const unsigned short* vb = (const unsigned short*)vh
            + (size_t)(b * LKV + kbeg) * DD + h * 64 + lane;
        for (int k = k0; k < k1; ++k) {
            float v = b2f(vb[(size_t)k * DD]);
#pragma unroll
            for (int qi = 0; qi < LQ; ++qi) acc[qi] += sc[qi][k] * v;
        }
#pragma unroll
        for (int qi = 0; qi < LQ; ++qi) paccs[w][qi][lane] = acc[qi];
    }
    __syncthreads();
    if (tid < 64) {
#pragma unroll
        for (int qi = 0; qi < LQ; ++qi) {
            float s = paccs[0][qi][tid] + paccs[1][qi][tid]
                    + paccs[2][qi][tid] + paccs[3][qi][tid];
            pacc[(size_t)((bh * 4 + qi) * NCH + c) * 64 + tid] = s;
        }
    }
    if (tid < LQ) {
        pm[(bh * 4 + tid) * NCH + c] = M[tid];
        pl[(bh * 4 + tid) * NCH + c] = L[tid];
    }
}

template<int LQ>
__global__ __launch_bounds__(256) void attn_comb_kernel(
    const float* __restrict__ pm, const float* __restrict__ pl,
    const float* __restrict__ pacc, float* __restrict__ out)
{
    int bh = blockIdx.x;
    int b = bh >> 4, h = bh & 15;
    int tid = threadIdx.x;
    int qi = tid >> 6, d = tid & 63;
    if (qi >= LQ) return;
    int base = (bh * 4 + qi) * NCH;
    float m0 = pm[base], m1 = pm[base+1], m2 = pm[base+2], m3 = pm[base+3];
    float M = fmaxf(fmaxf(m0, m1), fmaxf(m2, m3));
    float w0 = expf(m0 - M), w1 = expf(m1 - M), w2 = expf(m2 - M), w3 = expf(m3 - M);
    float L = pl[base]*w0 + pl[base+1]*w1 + pl[base+2]*w2 + pl[base+3]*w3;
    float A = pacc[(size_t)(base+0)*64 + d]*w0 + pacc[(size_t)(base+1)*64 + d]*w1
            + pacc[(size_t)(base+2)*64 + d]*w2 + pacc[(size_t)(base+3)*64 + d]*w3;
    out[(size_t)(b * LQ + qi) * DD + h * 64 + d] = A / L;
}

// ================= small copies / logits / gate ===============================
__global__ __launch_bounds__(256) void copy_lolast_kernel(
    const float* __restrict__ cat2, float* __restrict__ dst)
{
    int b = blockIdx.x;
    int tid = threadIdx.x;
#pragma unroll
    for (int i = 0; i < 4; ++i)
        dst[(size_t)b * DD + i * 256 + tid] =
            cat2[(size_t)(b * LKV + (TT - 1)) * DD + i * 256 + tid];
}

__global__ __launch_bounds__(256) void logits_kernel(
    const float* __restrict__ ln, const float* __restrict__ ctx, float* __restrict__ out)
{
    int r = blockIdx.x;
    int tid = threadIdx.x;
    float s = 0.f;
    for (int i = tid; i < DD; i += 256) s += ln[(size_t)r * DD + i] * ctx[i];
    s = warp_sum(s);
    __shared__ float a[4];
    if ((tid & 63) == 0) a[tid >> 6] = s;
    __syncthreads();
    if (tid == 0) out[r] = a[0] + a[1] + a[2] + a[3];
}

__global__ __launch_bounds__(256) void gate_kernel(
    const float* __restrict__ logits, const float* __restrict__ state_old,
    const float* __restrict__ lat2, float* __restrict__ stateNew,
    float* __restrict__ dout)
{
    int b = blockIdx.x;
    int tid = threadIdx.x;
    __shared__ float alpha[NS];
    if (tid == 0) {
        float l[NS];
        for (int s = 0; s < NS; ++s) l[s] = logits[b * NS + s];
        int i0 = 0;
        for (int s = 1; s < NS; ++s) if (l[s] > l[i0]) i0 = s;
        int i1 = (i0 == 0) ? 1 : 0;
        for (int s = 0; s < NS; ++s) if (s != i0 && l[s] > l[i1]) i1 = s;
        float mx = fmaxf(l[i0], l[i1]);
        float e0 = expf(l[i0] - mx), e1 = expf(l[i1] - mx);
        float inv = 1.f / (e0 + e1);
        for (int s = 0; s < NS; ++s) alpha[s] = 0.f;
        alpha[i0] = e0 * inv;
        alpha[i1] += e1 * inv;
        dout[4096 + b * 2 + 0] = (float)i0;
        dout[4096 + b * 2 + 1] = (float)i1;
    }
    __syncthreads();
    for (int idx = tid; idx < NS * DD; idx += 256) {
        int s = idx >> 10;
        float so = state_old[(size_t)b * NS * DD + idx];
        float lt = lat2[(size_t)b * NS * DD + idx];
        float ns = 0.6f * so + 0.4f * alpha[s] * tanhf(lt);
        stateNew[(size_t)b * NS * DD + idx] = ns;
        dout[4104 + b * NS * DD + idx] = ns;
    }
}

extern "C" void kernel_launch(void* const* d_in, const int* in_sizes, int n_in,
                              void* d_out, int out_size, void* d_ws, size_t ws_size,
                              hipStream_t stream)
{
    const float* x        = (const float*)d_in[0];
    const float* state0   = (const float*)d_in[1];
    const float* se_W     = (const float*)d_in[2];
    const float* se_b     = (const float*)d_in[3];
    const float* s_Wq     = (const float*)d_in[4];
    const float* s_bq     = (const float*)d_in[5];
    const float* s_Wk     = (const float*)d_in[6];
    const float* s_bk     = (const float*)d_in[7];
    const float* s_Wv     = (const float*)d_in[8];
    const float* s_bv     = (const float*)d_in[9];
    const float* s_Wo     = (const float*)d_in[10];
    const float* s_bo     = (const float*)d_in[11];
    const float* s_lnq_g  = (const float*)d_in[12];
    const float* s_lnq_b  = (const float*)d_in[13];
    const float* s_lnkv_g = (const float*)d_in[14];
    const float* s_lnkv_b = (const float*)d_in[15];
    const float* s_fc1_W  = (const float*)d_in[16];
    const float* s_fc1_b  = (const float*)d_in[17];
    const float* s_fc2_W  = (const float*)d_in[18];
    const float* s_fc2_b  = (const float*)d_in[19];
    const float* s_lnffn_g= (const float*)d_in[20];
    const float* s_lnffn_b= (const float*)d_in[21];
    const float* s_lnslot_g=(const float*)d_in[22];
    const float* s_lnslot_b=(const float*)d_in[23];
    const float* slot_ctx = (const float*)d_in[24];
    const float* oe_W     = (const float*)d_in[25];
    const float* oe_b     = (const float*)d_in[26];
    const float* o_Wq     = (const float*)d_in[27];
    const float* o_bq     = (const float*)d_in[28];
    const float* o_Wk     = (const float*)d_in[29];
    const float* o_bk     = (const float*)d_in[30];
    const float* o_Wv     = (const float*)d_in[31];
    const float* o_bv     = (const float*)d_in[32];
    const float* o_Wo     = (const float*)d_in[33];
    const float* o_bo     = (const float*)d_in[34];
    const float* o_lnq_g  = (const float*)d_in[35];
    const float* o_lnq_b  = (const float*)d_in[36];
    const float* o_lnkv_g = (const float*)d_in[37];
    const float* o_lnkv_b = (const float*)d_in[38];
    const float* o_fc1_W  = (const float*)d_in[39];
    const float* o_fc1_b  = (const float*)d_in[40];
    const float* o_fc2_W  = (const float*)d_in[41];
    const float* o_fc2_b  = (const float*)d_in[42];
    const float* o_lnffn_g= (const float*)d_in[43];
    const float* o_lnffn_b= (const float*)d_in[44];
    const float* op_W     = (const float*)d_in[45];
    const float* op_b     = (const float*)d_in[46];

    float* ws = (float*)d_ws;
    // Region plan (f32 offsets), with lifetime-based aliasing:
    //  pe    @ 0          (1,048,576)
    //  R1    @ 1,048,576  (4,210,688): cat (early) -> kh2 | vh2 (late)
    //  lnbb  @ 5,259,264  (2,162,688): bf16 4224 rows
    //  R2    @ 7,421,952  (4,210,688): cat2 (early) -> kh | vh (late)
    //  xb/lnbb2 @ 11,632,640 (2,097,152): bf16 4096 rows (xb early, lnbb2 late)
    //  wb    @ 13,729,792 (3,145,728): 6 bf16 weight matrices
    //  smalls@ 16,875,520
    float* pe   = ws;
    float* cat  = ws + 1048576;
    bf16*  kh2  = (bf16*)(ws + 1048576);
    bf16*  vh2  = (bf16*)(ws + 1048576 + 2105344);
    bf16*  lnbb = (bf16*)(ws + 5259264);
    float* cat2 = ws + 7421952;
    bf16*  kh   = (bf16*)(ws + 7421952);
    bf16*  vh   = (bf16*)(ws + 7421952 + 2105344);
    bf16*  xb   = (bf16*)(ws + 11632640);
    bf16*  lnbb2= (bf16*)(ws + 11632640);
    bf16*  wb   = (bf16*)(ws + 13729792);
    bf16*  seWb = wb;
    bf16*  oeWb = wb + 1048576;
    bf16*  sWkb = wb + 2097152;
    bf16*  sWvb = wb + 3145728;
    bf16*  oWkb = wb + 4194304;
    bf16*  oWvb = wb + 5242880;
    float* sm   = ws + 16875520;
    float* q_s     = sm;
    float* qh_s    = sm + 16384;
    float* attn_s  = sm + 32768;
    float* lat1    = sm + 49152;
    float* hffn    = sm + 65536;
    float* g1      = sm + 81920;
    float* lat2    = sm + 98304;
    float* lnslot  = sm + 114688;
    float* logitsb = sm + 131072;
    float* q2      = sm + 131136;
    float* q2h     = sm + 135232;
    float* attn2   = sm + 139328;
    float* lo_last = sm + 143424;
    float* lo1     = sm + 147520;
    float* h2      = sm + 151616;
    float* g2      = sm + 155712;
    float* lo2     = sm + 159808;
    float* pmb     = sm + 163904;
    float* plb     = sm + 164928;
    float* paccb   = sm + 165952;
    float* stateNew= sm + 231488;
    float* lnst    = sm + 247872;
    float* out = (float*)d_out;

    dim3 blk(256);

    // ---- phase 0: conversions + PE + state-row copy (one launch) ----
    PrepArgs pa;
    pa.cin[0] = x;    pa.cout[0] = xb;
    pa.cin[1] = se_W; pa.cout[1] = seWb;
    pa.cin[2] = oe_W; pa.cout[2] = oeWb;
    pa.cin[3] = s_Wk; pa.cout[3] = sWkb;
    pa.cin[4] = s_Wv; pa.cout[4] = sWvb;
    pa.cin[5] = o_Wk; pa.cout[5] = oWkb;
    pa.cin[6] = o_Wv; pa.cout[6] = oWvb;
    pa.state0 = state0; pa.cat = cat; pa.pe = pe;
    prep_kernel<<<11280, blk, 0, stream>>>(pa);

    // ---- phase 1: both embeds fused (2 blocks/CU) ----
    embed_fused_kernel<<<dim3(8, 32, 2), blk, 0, stream>>>(
        xb, seWb, oeWb, se_b, oe_b, cat, cat2, pe);

    // ---- phase 2: all row-wise LNs + extracts (independent of gate) ----
    ln_fused_kernel<<<8208, blk, 0, stream>>>(cat, cat2, lnbb, lnbb2,
        s_lnkv_g, s_lnkv_b, o_lnkv_g, o_lnkv_b);
    ln_kernel<<<16, blk, 0, stream>>>(state0, q_s, s_lnq_g, s_lnq_b, 0, 1);
    ln_kernel<<<NB, blk, 0, stream>>>(cat2, q2, o_lnq_g, o_lnq_b, TT - 1, LKV);
    copy_lolast_kernel<<<NB, blk, 0, stream>>>(cat2, lo_last);
    small_gemm_kernel<16><<<256, blk, 0, stream>>>(q_s, s_Wq, s_bq, qh_s, nullptr, 0, nullptr, 0);
    small_gemm_kernel<4><<<256, blk, 0, stream>>>(q2, o_Wq, o_bq, q2h, nullptr, 0, nullptr, 0);

    // ---- phase 3: all four K/V GEMMs fused (4 blocks/CU). Overwrites cat/cat2. ----
    kv_fused_kernel<<<dim3(8, 33, 4), blk, 0, stream>>>(
        lnbb, lnbb2, sWkb, sWvb, oWkb, oWvb,
        s_bk, s_bv, o_bk, o_bv, kh, vh, kh2, vh2);

    // ---- phase 4: state-branch attention + slot update ----
    attn_part_kernel<4><<<256, blk, 0, stream>>>(qh_s, kh, vh, pmb, plb, paccb);
    attn_comb_kernel<4><<<64, blk, 0, stream>>>(pmb, plb, paccb, attn_s);
    small_gemm_kernel<16><<<256, blk, 0, stream>>>(attn_s, s_Wo, s_bo, lat1, nullptr, 0, state0, 0);
    ln_kernel<<<16, blk, 0, stream>>>(lat1, hffn, s_lnffn_g, s_lnffn_b, 0, 1);
    small_gemm_kernel<16><<<256, blk, 0, stream>>>(hffn, s_fc1_W, s_fc1_b, g1, nullptr, 0, nullptr, 1);
    small_gemm_kernel<16><<<256, blk, 0, stream>>>(g1, s_fc2_W, s_fc2_b, lat2, nullptr, 0, lat1, 0);
    ln_kernel<<<16, blk, 0, stream>>>(lat2, lnslot, s_lnslot_g, s_lnslot_b, 0, 1);
    logits_kernel<<<16, blk, 0, stream>>>(lnslot, slot_ctx, logitsb);
    gate_kernel<<<NB, blk, 0, stream>>>(logitsb, state0, lat2, stateNew, out);

    // ---- phase 5: complete out-branch K/V with the 16 new-state rows ----
    ln_kernel<<<16, blk, 0, stream>>>(stateNew, lnst, o_lnkv_g, o_lnkv_b, 0, 1);
    small_gemm_kernel<16><<<256, blk, 0, stream>>>(lnst, o_Wk, o_bk, nullptr, kh2, 1, nullptr, 0);
    small_gemm_kernel<16><<<256, blk, 0, stream>>>(lnst, o_Wv, o_bv, nullptr, vh2, 1, nullptr, 0);

    // ---- phase 6: out-branch attention (last token only) + head ----
    attn_part_kernel<1><<<256, blk, 0, stream>>>(q2h, kh2, vh2, pmb, plb, paccb);
    attn_comb_kernel<1><<<64, blk, 0, stream>>>(pmb, plb, paccb, attn2);
    small_gemm_kernel<4><<<256, blk, 0, stream>>>(attn2, o_Wo, o_bo, lo1, nullptr, 0, lo_last, 0);
    ln_kernel<<<NB, blk, 0, stream>>>(lo1, h2, o_lnffn_g, o_lnffn_b, 0, 1);
    small_gemm_kernel<4><<<256, blk, 0, stream>>>(h2, o_fc1_W, o_fc1_b, g2, nullptr, 0, nullptr, 1);
    small_gemm_kernel<4><<<256, blk, 0, stream>>>(g2, o_fc2_W, o_fc2_b, lo2, nullptr, 0, lo1, 0);
    small_gemm_kernel<4><<<256, blk, 0, stream>>>(lo2, op_W, op_b, out, nullptr, 0, nullptr, 0);
}

// Round 7
// 274.228 us; speedup vs baseline: 10.1200x; 1.0402x over previous
//
#include <hip/hip_runtime.h>
#include <hip/hip_bf16.h>

#define DD 1024
#define NB 4
#define TT 1024
#define NH 16
#define NS 4
#define LKV 1028   // NS + TT
#define NCH 4
#define CHS 257    // keys per chunk (4*257 = 1028)

typedef __hip_bfloat16 bf16;
typedef __attribute__((ext_vector_type(8))) short short8;
typedef __attribute__((ext_vector_type(4))) float f32x4;

#define GLD16(gp, lp) __builtin_amdgcn_global_load_lds( \
    (const __attribute__((address_space(1))) unsigned int*)(const void*)(gp), \
    (__attribute__((address_space(3))) unsigned int*)(void*)(lp), 16, 0, 0)

__device__ __forceinline__ float warp_sum(float v) {
#pragma unroll
    for (int o = 32; o > 0; o >>= 1) v += __shfl_xor(v, o);
    return v;
}

__device__ __forceinline__ float b2f(unsigned short u) {
    union { unsigned int i; float f; } x; x.i = ((unsigned)u) << 16; return x.f;
}

// ================= prep: cvt x + 6 weights, PE table, state-row copy ==========
struct PrepArgs {
    const float* cin[7];   // x, seW, oeW, sWk, sWv, oWk, oWv
    bf16* cout[7];
    const float* state0;
    float* cat;
    float* pe;
};

__global__ __launch_bounds__(256) void prep_kernel(PrepArgs a) {
    int bid = blockIdx.x;
    int tid = threadIdx.x;
    if (bid < 10240) {
        const float* in; bf16* out; size_t off;
        if (bid < 4096) { in = a.cin[0]; out = a.cout[0]; off = (size_t)bid * 1024; }
        else {
            int w = (bid - 4096) >> 10;
            in = a.cin[1 + w]; out = a.cout[1 + w];
            off = (size_t)((bid - 4096) & 1023) * 1024;
        }
        size_t i = off + tid * 4;
        float4 v = *(const float4*)(in + i);
        out[i + 0] = __float2bfloat16(v.x);
        out[i + 1] = __float2bfloat16(v.y);
        out[i + 2] = __float2bfloat16(v.z);
        out[i + 3] = __float2bfloat16(v.w);
    } else if (bid < 11264) {
        int t = bid - 10240;
#pragma unroll
        for (int i = 0; i < 2; ++i) {
            int j = i * 256 + tid;                       // 0..511
            float ang = (float)t * exp2f(-(float)j * (1.0f / 256.0f));
            a.pe[(size_t)t * DD + j]       = sinf(ang);
            a.pe[(size_t)t * DD + 512 + j] = cosf(ang);
        }
    } else {
        int r = bid - 11264;       // 0..15
        int b = r >> 2, s = r & 3;
#pragma unroll
        for (int i = 0; i < 4; ++i)
            a.cat[(size_t)(b * LKV + s) * DD + i * 256 + tid] =
                a.state0[(size_t)r * DD + i * 256 + tid];
    }
}

// ================= fused LayerNorm -> bf16 (state-kv rows + out token rows) ===
__global__ __launch_bounds__(256) void ln_fused_kernel(
    const float* __restrict__ cat, const float* __restrict__ cat2,
    bf16* __restrict__ lnbb, bf16* __restrict__ lnbb2,
    const float* __restrict__ sg, const float* __restrict__ sb,
    const float* __restrict__ og, const float* __restrict__ ob)
{
    int bid = blockIdx.x;
    int tid = threadIdx.x;
    const float* in; bf16* out; const float* g; const float* b;
    if (bid < 4112) {
        in = cat + (size_t)bid * DD; out = lnbb + (size_t)bid * DD; g = sg; b = sb;
    } else {
        int r = bid - 4112;
        int row = (r >> 10) * LKV + (r & 1023);
        in = cat2 + (size_t)row * DD; out = lnbb2 + (size_t)r * DD; g = og; b = ob;
    }
    float v[4];
    float s1 = 0.f, s2 = 0.f;
#pragma unroll
    for (int i = 0; i < 4; ++i) {
        v[i] = in[i * 256 + tid];
        s1 += v[i]; s2 += v[i] * v[i];
    }
    s1 = warp_sum(s1); s2 = warp_sum(s2);
    __shared__ float a1[4], a2[4];
    int w = tid >> 6;
    if ((tid & 63) == 0) { a1[w] = s1; a2[w] = s2; }
    __syncthreads();
    s1 = a1[0] + a1[1] + a1[2] + a1[3];
    s2 = a2[0] + a2[1] + a2[2] + a2[3];
    float mu  = s1 * (1.0f / DD);
    float var = s2 * (1.0f / DD) - mu * mu;
    var = var < 0.f ? 0.f : var;
    float rs = rsqrtf(var + 1e-5f);
#pragma unroll
    for (int i = 0; i < 4; ++i) {
        int c = i * 256 + tid;
        out[c] = __float2bfloat16((v[i] - mu) * rs * g[c] + b[c]);
    }
}

// ================= MFMA tile body (128x128, BK=32, 4 waves) ===================
__device__ __forceinline__ void mfma_tile(
    const bf16* __restrict__ A, const bf16* __restrict__ W,
    const float* __restrict__ bias,
    float* __restrict__ outf, bf16* __restrict__ outb,
    int M, int obs, int oro, const float* __restrict__ pe,
    bf16* As, bf16* Ws, int m0, int n0)
{
    int tid  = threadIdx.x;
    int lane = tid & 63;
    int wave = tid >> 6;
    int wm = (wave >> 1) << 6;
    int wn = (wave & 1) << 6;

    f32x4 acc[4][4] = {};

    int soff  = wave * 1024 + lane * 16;
    int srow  = soff >> 6;
    int scol  = (soff & 63) >> 1;
    char* lA0 = (char*)As + wave * 1024;
    char* lA1 = (char*)As + 4096 + wave * 1024;
    char* lW0 = (char*)Ws + wave * 1024;
    char* lW1 = (char*)Ws + 4096 + wave * 1024;

    int fRow = lane & 15;
    int kOff = (lane >> 4) << 3;

    for (int k0 = 0; k0 < DD; k0 += 32) {
        GLD16(A + (size_t)(m0 + srow) * DD + k0 + scol,      lA0);
        GLD16(A + (size_t)(m0 + 64 + srow) * DD + k0 + scol, lA1);
        GLD16(W + (size_t)(n0 + srow) * DD + k0 + scol,      lW0);
        GLD16(W + (size_t)(n0 + 64 + srow) * DD + k0 + scol, lW1);
        __syncthreads();
        short8 a[4], b[4];
#pragma unroll
        for (int mi = 0; mi < 4; ++mi)
            a[mi] = *(const short8*)(As + (wm + mi * 16 + fRow) * 32 + kOff);
#pragma unroll
        for (int ni = 0; ni < 4; ++ni)
            b[ni] = *(const short8*)(Ws + (wn + ni * 16 + fRow) * 32 + kOff);
#pragma unroll
        for (int mi = 0; mi < 4; ++mi)
#pragma unroll
            for (int ni = 0; ni < 4; ++ni)
                acc[mi][ni] = __builtin_amdgcn_mfma_f32_16x16x32_bf16(
                    a[mi], b[ni], acc[mi][ni], 0, 0, 0);
        __syncthreads();
    }

    int cCol  = lane & 15;
    int cRow4 = (lane >> 4) << 2;
#pragma unroll
    for (int mi = 0; mi < 4; ++mi) {
#pragma unroll
        for (int ni = 0; ni < 4; ++ni) {
#pragma unroll
            for (int r = 0; r < 4; ++r) {
                int row = m0 + wm + mi * 16 + cRow4 + r;
                int col = n0 + wn + ni * 16 + cCol;
                if (row < M) {
                    float v = acc[mi][ni][r] + bias[col];
                    if (outf) {
                        v += pe[(size_t)(row & 1023) * DD + col];
                        int orow = (row >> 10) * obs + oro + (row & 1023);
                        outf[(size_t)orow * DD + col] = v;
                    } else {
                        int orow = obs ? ((row >> 10) * obs + (row & 1023)) : row;
                        outb[(size_t)orow * DD + col] = __float2bfloat16(v);
                    }
                }
            }
        }
    }
}

// ================= fused embeds, XCD-swizzled linear grid (512 blocks) ========
// tile order: t = (y*2 + z)*8 + x  (col fastest, both gemms share A panel y)
__global__ __launch_bounds__(256) void embed_fused_kernel(
    const bf16* __restrict__ xb,
    const bf16* __restrict__ seW, const bf16* __restrict__ oeW,
    const float* __restrict__ seb, const float* __restrict__ oeb,
    float* __restrict__ cat, float* __restrict__ cat2,
    const float* __restrict__ pe)
{
    __shared__ bf16 As[128 * 32];
    __shared__ bf16 Ws[128 * 32];
    int bid = blockIdx.x;
    int t = (bid & 7) * 64 + (bid >> 3);   // bijective XCD swizzle (512 = 8*64)
    int x = t & 7;
    int q = t >> 3;
    int z = q & 1;
    int y = q >> 1;
    const bf16* W = z ? oeW : seW;
    const float* bias = z ? oeb : seb;
    float* outf = z ? cat2 : cat;
    int oro = z ? 0 : NS;
    mfma_tile(xb, W, bias, outf, nullptr, 4096, LKV, oro, pe, As, Ws,
              y * 128, x * 128);
}

// ================= fused K/V GEMMs, XCD-swizzled linear grid (1056 blocks) ====
// tile order: t = ((zp*33 + y)*2 + zi)*8 + x ; z = zp*2+zi
__global__ __launch_bounds__(256) void kv_fused_kernel(
    const bf16* __restrict__ lnbb, const bf16* __restrict__ lnbb2,
    const bf16* __restrict__ W0, const bf16* __restrict__ W1,
    const bf16* __restrict__ W2, const bf16* __restrict__ W3,
    const float* __restrict__ b0, const float* __restrict__ b1,
    const float* __restrict__ b2, const float* __restrict__ b3,
    bf16* __restrict__ o0, bf16* __restrict__ o1,
    bf16* __restrict__ o2, bf16* __restrict__ o3)
{
    __shared__ bf16 As[128 * 32];
    __shared__ bf16 Ws[128 * 32];
    int bid = blockIdx.x;
    int t = (bid & 7) * 132 + (bid >> 3);  // bijective XCD swizzle (1056 = 8*132)
    int x = t & 7;
    int u = t >> 3;          // 0..131
    int zi = u & 1;
    int v = u >> 1;          // 0..65
    int y = v % 33;
    int zp = v / 33;
    int z = zp * 2 + zi;
    const bf16* Warr[4] = {W0, W1, W2, W3};
    const float* barr[4] = {b0, b1, b2, b3};
    bf16* oarr[4] = {o0, o1, o2, o3};
    const bf16* A = (zp == 0) ? lnbb : lnbb2;
    int M   = (zp == 0) ? 4112 : 4096;
    int obs = (zp == 0) ? 0 : LKV;
    mfma_tile(A, Warr[z], barr[z], nullptr, oarr[z], M, obs, 0, nullptr, As, Ws,
              y * 128, x * 128);
}

// ================= small GEMM (M<=16): one wave per output column =============
template<int M>
__global__ __launch_bounds__(256) void small_gemm_kernel(
    const float* __restrict__ A, const float* __restrict__ W,
    const float* __restrict__ bias, float* __restrict__ outf,
    const float* __restrict__ res, int gelu)
{
    __shared__ float As[M * DD];
    int tid = threadIdx.x;
#pragma unroll
    for (int i = 0; i < M; ++i) {
        int idx = (i * 256 + tid) * 4;
        *(float4*)(As + idx) = *(const float4*)(A + idx);
    }
    __syncthreads();
    int lane = tid & 63;
    int w = tid >> 6;
    int n = blockIdx.x * 4 + w;
    const float* Wr = W + (size_t)n * DD;
    float acc[M] = {};
#pragma unroll
    for (int j = 0; j < 4; ++j) {
        float4 wv = *(const float4*)(Wr + j * 256 + lane * 4);
#pragma unroll
        for (int m = 0; m < M; ++m) {
            float4 av = *(const float4*)(As + m * DD + j * 256 + lane * 4);
            acc[m] += av.x * wv.x + av.y * wv.y + av.z * wv.z + av.w * wv.w;
        }
    }
#pragma unroll
    for (int m = 0; m < M; ++m) acc[m] = warp_sum(acc[m]);
    if (lane == 0) {
#pragma unroll
        for (int m = 0; m < M; ++m) {
            float v = acc[m] + bias[n];
            if (gelu) v = 0.5f * v * (1.0f + erff(v * 0.70710678118654752f));
            if (res)  v += res[(size_t)m * DD + n];
            outf[(size_t)m * DD + n] = v;
        }
    }
}

// ============ small GEMM with fused input LayerNorm: C = LN(A) @ W^T + b ======
// A rows: row0 + i*rstride. outb!=null => bf16 out with remap (state KV rows).
template<int M>
__global__ __launch_bounds__(256) void small_ln_gemm_kernel(
    const float* __restrict__ A, int row0, int rstride,
    const float* __restrict__ lng, const float* __restrict__ lnb,
    const float* __restrict__ W, const float* __restrict__ bias,
    float* __restrict__ outf, bf16* __restrict__ outb, int gelu)
{
    __shared__ float As[M * DD];
    __shared__ float smu[M], srs[M];
    int tid = threadIdx.x;
    int lane = tid & 63;
    int w = tid >> 6;
#pragma unroll
    for (int i = 0; i < M; ++i) {
        int row = row0 + i * rstride;
        *(float4*)(As + i * DD + tid * 4) =
            *(const float4*)(A + (size_t)row * DD + tid * 4);
    }
    __syncthreads();
    constexpr int RPW = (M + 3) / 4;
#pragma unroll
    for (int i = 0; i < RPW; ++i) {
        int r = w * RPW + i;
        if (r < M) {
            float s1 = 0.f, s2 = 0.f;
#pragma unroll
            for (int j = 0; j < 4; ++j) {
                float4 v = *(const float4*)(As + r * DD + (j * 64 + lane) * 4);
                s1 += v.x + v.y + v.z + v.w;
                s2 += v.x*v.x + v.y*v.y + v.z*v.z + v.w*v.w;
            }
            s1 = warp_sum(s1); s2 = warp_sum(s2);
            if (lane == 0) {
                float mu = s1 * (1.0f / DD);
                float var = s2 * (1.0f / DD) - mu * mu;
                var = var < 0.f ? 0.f : var;
                smu[r] = mu; srs[r] = rsqrtf(var + 1e-5f);
            }
        }
    }
    __syncthreads();
    float4 gv = *(const float4*)(lng + tid * 4);
    float4 bv = *(const float4*)(lnb + tid * 4);
#pragma unroll
    for (int i = 0; i < M; ++i) {
        float mu = smu[i], rs = srs[i];
        float4 v = *(const float4*)(As + i * DD + tid * 4);
        v.x = (v.x - mu) * rs * gv.x + bv.x;
        v.y = (v.y - mu) * rs * gv.y + bv.y;
        v.z = (v.z - mu) * rs * gv.z + bv.z;
        v.w = (v.w - mu) * rs * gv.w + bv.w;
        *(float4*)(As + i * DD + tid * 4) = v;
    }
    __syncthreads();
    int n = blockIdx.x * 4 + w;
    const float* Wr = W + (size_t)n * DD;
    float acc[M] = {};
#pragma unroll
    for (int j = 0; j < 4; ++j) {
        float4 wv = *(const float4*)(Wr + j * 256 + lane * 4);
#pragma unroll
        for (int m = 0; m < M; ++m) {
            float4 av = *(const float4*)(As + m * DD + j * 256 + lane * 4);
            acc[m] += av.x * wv.x + av.y * wv.y + av.z * wv.z + av.w * wv.w;
        }
    }
#pragma unroll
    for (int m = 0; m < M; ++m) acc[m] = warp_sum(acc[m]);
    if (lane == 0) {
#pragma unroll
        for (int m = 0; m < M; ++m) {
            float v = acc[m] + bias[n];
            if (gelu) v = 0.5f * v * (1.0f + erff(v * 0.70710678118654752f));
            if (outb) {
                int orow = (m >> 2) * LKV + TT + (m & 3);
                outb[(size_t)orow * DD + n] = __float2bfloat16(v);
            } else {
                outf[(size_t)m * DD + n] = v;
            }
        }
    }
}

// ================= split-K flash-decode attention =============================
template<int LQ>
__global__ __launch_bounds__(256) void attn_part_kernel(
    const float* __restrict__ qh, const bf16* __restrict__ kh,
    const bf16* __restrict__ vh, float* __restrict__ pm,
    float* __restrict__ pl, float* __restrict__ pacc)
{
    int blk = blockIdx.x;
    int c  = blk & (NCH - 1);
    int bh = blk >> 2;
    int b = bh >> 4, h = bh & 15;
    int tid = threadIdx.x;
    int lane = tid & 63, w = tid >> 6;

    __shared__ float qs[LQ][64];
    __shared__ float sc[LQ][CHS];
    __shared__ float redm[4][LQ];
    __shared__ float redl[4][LQ];
    __shared__ float paccs[4][LQ][64];

    if (w < LQ) qs[w][lane] = qh[(size_t)(b * LQ + w) * DD + h * 64 + lane];
    __syncthreads();

    int kbeg = c * CHS;
    for (int t = tid; t < CHS; t += 256) {
        const ushort4* kr = (const ushort4*)((const unsigned short*)kh
            + (size_t)(b * LKV + kbeg + t) * DD + h * 64);
        float kf[64];
#pragma unroll
        for (int i = 0; i < 16; ++i) {
            ushort4 kk = kr[i];
            kf[i*4+0] = b2f(kk.x); kf[i*4+1] = b2f(kk.y);
            kf[i*4+2] = b2f(kk.z); kf[i*4+3] = b2f(kk.w);
        }
#pragma unroll
        for (int qi = 0; qi < LQ; ++qi) {
            float s = 0.f;
#pragma unroll
            for (int d = 0; d < 64; ++d) s += qs[qi][d] * kf[d];
            sc[qi][t] = s * 0.125f;
        }
    }
    __syncthreads();

    float M[LQ], L[LQ];
#pragma unroll
    for (int qi = 0; qi < LQ; ++qi) {
        float lm = -1e30f;
        for (int t = tid; t < CHS; t += 256) lm = fmaxf(lm, sc[qi][t]);
#pragma unroll
        for (int o = 32; o > 0; o >>= 1) lm = fmaxf(lm, __shfl_xor(lm, o));
        if (lane == 0) redm[w][qi] = lm;
    }
    __syncthreads();
#pragma unroll
    for (int qi = 0; qi < LQ; ++qi)
        M[qi] = fmaxf(fmaxf(redm[0][qi], redm[1][qi]), fmaxf(redm[2][qi], redm[3][qi]));

#pragma unroll
    for (int qi = 0; qi < LQ; ++qi) {
        float ls = 0.f;
        for (int t = tid; t < CHS; t += 256) {
            float e = expf(sc[qi][t] - M[qi]);
            sc[qi][t] = e;
            ls += e;
        }
        ls = warp_sum(ls);
        if (lane == 0) redl[w][qi] = ls;
    }
    __syncthreads();
#pragma unroll
    for (int qi = 0; qi < LQ; ++qi)
        L[qi] = redl[0][qi] + redl[1][qi] + redl[2][qi] + redl[3][qi];

    {
        int k0 = w * 65;
        int k1 = (k0 + 65 < CHS) ? k0 + 65 : CHS;
        float acc[LQ] = {};
        const unsigned short* vb = (const unsigned short*)vh
            + (size_t)(b * LKV + kbeg) * DD + h * 64 + lane;
        for (int k = k0; k < k1; ++k) {
            float v = b2f(vb[(size_t)k * DD]);
#pragma unroll
            for (int qi = 0; qi < LQ; ++qi) acc[qi] += sc[qi][k] * v;
        }
#pragma unroll
        for (int qi = 0; qi < LQ; ++qi) paccs[w][qi][lane] = acc[qi];
    }
    __syncthreads();
    if (tid < 64) {
#pragma unroll
        for (int qi = 0; qi < LQ; ++qi) {
            float s = paccs[0][qi][tid] + paccs[1][qi][tid]
                    + paccs[2][qi][tid] + paccs[3][qi][tid];
            pacc[(size_t)((bh * 4 + qi) * NCH + c) * 64 + tid] = s;
        }
    }
    if (tid < LQ) {
        pm[(bh * 4 + tid) * NCH + c] = M[tid];
        pl[(bh * 4 + tid) * NCH + c] = L[tid];
    }
}

template<int LQ>
__global__ __launch_bounds__(256) void attn_comb_kernel(
    const float* __restrict__ pm, const float* __restrict__ pl,
    const float* __restrict__ pacc, float* __restrict__ out)
{
    int bh = blockIdx.x;
    int b = bh >> 4, h = bh & 15;
    int tid = threadIdx.x;
    int qi = tid >> 6, d = tid & 63;
    if (qi >= LQ) return;
    int base = (bh * 4 + qi) * NCH;
    float m0 = pm[base], m1 = pm[base+1], m2 = pm[base+2], m3 = pm[base+3];
    float M = fmaxf(fmaxf(m0, m1), fmaxf(m2, m3));
    float w0 = expf(m0 - M), w1 = expf(m1 - M), w2 = expf(m2 - M), w3 = expf(m3 - M);
    float L = pl[base]*w0 + pl[base+1]*w1 + pl[base+2]*w2 + pl[base+3]*w3;
    float A = pacc[(size_t)(base+0)*64 + d]*w0 + pacc[(size_t)(base+1)*64 + d]*w1
            + pacc[(size_t)(base+2)*64 + d]*w2 + pacc[(size_t)(base+3)*64 + d]*w3;
    out[(size_t)(b * LQ + qi) * DD + h * 64 + d] = A / L;
}

// ================= copy lo[:, -1] =============================================
__global__ __launch_bounds__(256) void copy_lolast_kernel(
    const float* __restrict__ cat2, float* __restrict__ dst)
{
    int b = blockIdx.x;
    int tid = threadIdx.x;
#pragma unroll
    for (int i = 0; i < 4; ++i)
        dst[(size_t)b * DD + i * 256 + tid] =
            cat2[(size_t)(b * LKV + (TT - 1)) * DD + i * 256 + tid];
}

// ========== fused gate: LN(lat2) -> logits -> top2 -> state update ============
// grid NB; wave w handles slot s=w (lat2 row b*4+w).
__global__ __launch_bounds__(256) void gate_fused_kernel(
    const float* __restrict__ lat2,
    const float* __restrict__ lng, const float* __restrict__ lnb,
    const float* __restrict__ ctx,
    const float* __restrict__ state_old, float* __restrict__ stateNew,
    float* __restrict__ dout)
{
    int b = blockIdx.x;
    int tid = threadIdx.x;
    int lane = tid & 63, w = tid >> 6;
    __shared__ float logit[NS];
    __shared__ float alpha[NS];

    {
        const float* row = lat2 + (size_t)(b * NS + w) * DD;
        float4 v[4];
        float s1 = 0.f, s2 = 0.f;
#pragma unroll
        for (int j = 0; j < 4; ++j) {
            v[j] = *(const float4*)(row + (j * 64 + lane) * 4);
            s1 += v[j].x + v[j].y + v[j].z + v[j].w;
            s2 += v[j].x*v[j].x + v[j].y*v[j].y + v[j].z*v[j].z + v[j].w*v[j].w;
        }
        s1 = warp_sum(s1); s2 = warp_sum(s2);
        float mu = s1 * (1.0f / DD);
        float var = s2 * (1.0f / DD) - mu * mu;
        var = var < 0.f ? 0.f : var;
        float rs = rsqrtf(var + 1e-5f);
        float dot = 0.f;
#pragma unroll
        for (int j = 0; j < 4; ++j) {
            int c = (j * 64 + lane) * 4;
            float4 gv = *(const float4*)(lng + c);
            float4 bv = *(const float4*)(lnb + c);
            float4 cv = *(const float4*)(ctx + c);
            dot += ((v[j].x - mu) * rs * gv.x + bv.x) * cv.x
                 + ((v[j].y - mu) * rs * gv.y + bv.y) * cv.y
                 + ((v[j].z - mu) * rs * gv.z + bv.z) * cv.z
                 + ((v[j].w - mu) * rs * gv.w + bv.w) * cv.w;
        }
        dot = warp_sum(dot);
        if (lane == 0) logit[w] = dot;
    }
    __syncthreads();
    if (tid == 0) {
        float l[NS];
        for (int s = 0; s < NS; ++s) l[s] = logit[s];
        int i0 = 0;
        for (int s = 1; s < NS; ++s) if (l[s] > l[i0]) i0 = s;
        int i1 = (i0 == 0) ? 1 : 0;
        for (int s = 0; s < NS; ++s) if (s != i0 && l[s] > l[i1]) i1 = s;
        float mx = fmaxf(l[i0], l[i1]);
        float e0 = expf(l[i0] - mx), e1 = expf(l[i1] - mx);
        float inv = 1.f / (e0 + e1);
        for (int s = 0; s < NS; ++s) alpha[s] = 0.f;
        alpha[i0] = e0 * inv;
        alpha[i1] += e1 * inv;
        dout[4096 + b * 2 + 0] = (float)i0;
        dout[4096 + b * 2 + 1] = (float)i1;
    }
    __syncthreads();
    for (int idx = tid; idx < NS * DD; idx += 256) {
        int s = idx >> 10;
        float so = state_old[(size_t)b * NS * DD + idx];
        float lt = lat2[(size_t)b * NS * DD + idx];
        float ns = 0.6f * so + 0.4f * alpha[s] * tanhf(lt);
        stateNew[(size_t)b * NS * DD + idx] = ns;
        dout[4104 + b * NS * DD + idx] = ns;
    }
}

extern "C" void kernel_launch(void* const* d_in, const int* in_sizes, int n_in,
                              void* d_out, int out_size, void* d_ws, size_t ws_size,
                              hipStream_t stream)
{
    const float* x        = (const float*)d_in[0];
    const float* state0   = (const float*)d_in[1];
    const float* se_W     = (const float*)d_in[2];
    const float* se_b     = (const float*)d_in[3];
    const float* s_Wq     = (const float*)d_in[4];
    const float* s_bq     = (const float*)d_in[5];
    const float* s_Wk     = (const float*)d_in[6];
    const float* s_bk     = (const float*)d_in[7];
    const float* s_Wv     = (const float*)d_in[8];
    const float* s_bv     = (const float*)d_in[9];
    const float* s_Wo     = (const float*)d_in[10];
    const float* s_bo     = (const float*)d_in[11];
    const float* s_lnq_g  = (const float*)d_in[12];
    const float* s_lnq_b  = (const float*)d_in[13];
    const float* s_lnkv_g = (const float*)d_in[14];
    const float* s_lnkv_b = (const float*)d_in[15];
    const float* s_fc1_W  = (const float*)d_in[16];
    const float* s_fc1_b  = (const float*)d_in[17];
    const float* s_fc2_W  = (const float*)d_in[18];
    const float* s_fc2_b  = (const float*)d_in[19];
    const float* s_lnffn_g= (const float*)d_in[20];
    const float* s_lnffn_b= (const float*)d_in[21];
    const float* s_lnslot_g=(const float*)d_in[22];
    const float* s_lnslot_b=(const float*)d_in[23];
    const float* slot_ctx = (const float*)d_in[24];
    const float* oe_W     = (const float*)d_in[25];
    const float* oe_b     = (const float*)d_in[26];
    const float* o_Wq     = (const float*)d_in[27];
    const float* o_bq     = (const float*)d_in[28];
    const float* o_Wk     = (const float*)d_in[29];
    const float* o_bk     = (const float*)d_in[30];
    const float* o_Wv     = (const float*)d_in[31];
    const float* o_bv     = (const float*)d_in[32];
    const float* o_Wo     = (const float*)d_in[33];
    const float* o_bo     = (const float*)d_in[34];
    const float* o_lnq_g  = (const float*)d_in[35];
    const float* o_lnq_b  = (const float*)d_in[36];
    const float* o_lnkv_g = (const float*)d_in[37];
    const float* o_lnkv_b = (const float*)d_in[38];
    const float* o_fc1_W  = (const float*)d_in[39];
    const float* o_fc1_b  = (const float*)d_in[40];
    const float* o_fc2_W  = (const float*)d_in[41];
    const float* o_fc2_b  = (const float*)d_in[42];
    const float* o_lnffn_g= (const float*)d_in[43];
    const float* o_lnffn_b= (const float*)d_in[44];
    const float* op_W     = (const float*)d_in[45];
    const float* op_b     = (const float*)d_in[46];

    float* ws = (float*)d_ws;
    float* pe   = ws;
    float* cat  = ws + 1048576;
    bf16*  kh2  = (bf16*)(ws + 1048576);
    bf16*  vh2  = (bf16*)(ws + 1048576 + 2105344);
    bf16*  lnbb = (bf16*)(ws + 5259264);
    float* cat2 = ws + 7421952;
    bf16*  kh   = (bf16*)(ws + 7421952);
    bf16*  vh   = (bf16*)(ws + 7421952 + 2105344);
    bf16*  xb   = (bf16*)(ws + 11632640);
    bf16*  lnbb2= (bf16*)(ws + 11632640);
    bf16*  wb   = (bf16*)(ws + 13729792);
    bf16*  seWb = wb;
    bf16*  oeWb = wb + 1048576;
    bf16*  sWkb = wb + 2097152;
    bf16*  sWvb = wb + 3145728;
    bf16*  oWkb = wb + 4194304;
    bf16*  oWvb = wb + 5242880;
    float* sm   = ws + 16875520;
    float* qh_s    = sm + 16384;
    float* attn_s  = sm + 32768;
    float* lat1    = sm + 49152;
    float* g1      = sm + 81920;
    float* lat2    = sm + 98304;
    float* q2h     = sm + 135232;
    float* attn2   = sm + 139328;
    float* lo_last = sm + 143424;
    float* lo1     = sm + 147520;
    float* g2      = sm + 155712;
    float* lo2     = sm + 159808;
    float* pmb     = sm + 163904;
    float* plb     = sm + 164928;
    float* paccb   = sm + 165952;
    float* stateNew= sm + 231488;
    float* out = (float*)d_out;

    dim3 blk(256);

    // ---- phase 0: conversions + PE + state-row copy ----
    PrepArgs pa;
    pa.cin[0] = x;    pa.cout[0] = xb;
    pa.cin[1] = se_W; pa.cout[1] = seWb;
    pa.cin[2] = oe_W; pa.cout[2] = oeWb;
    pa.cin[3] = s_Wk; pa.cout[3] = sWkb;
    pa.cin[4] = s_Wv; pa.cout[4] = sWvb;
    pa.cin[5] = o_Wk; pa.cout[5] = oWkb;
    pa.cin[6] = o_Wv; pa.cout[6] = oWvb;
    pa.state0 = state0; pa.cat = cat; pa.pe = pe;
    prep_kernel<<<11280, blk, 0, stream>>>(pa);

    // ---- phase 1: both embeds, XCD-swizzled ----
    embed_fused_kernel<<<512, blk, 0, stream>>>(
        xb, seWb, oeWb, se_b, oe_b, cat, cat2, pe);

    // ---- phase 2: row-wise LNs + q projections (gate-independent) ----
    ln_fused_kernel<<<8208, blk, 0, stream>>>(cat, cat2, lnbb, lnbb2,
        s_lnkv_g, s_lnkv_b, o_lnkv_g, o_lnkv_b);
    copy_lolast_kernel<<<NB, blk, 0, stream>>>(cat2, lo_last);
    small_ln_gemm_kernel<16><<<256, blk, 0, stream>>>(state0, 0, 1,
        s_lnq_g, s_lnq_b, s_Wq, s_bq, qh_s, nullptr, 0);
    small_ln_gemm_kernel<4><<<256, blk, 0, stream>>>(cat2, TT - 1, LKV,
        o_lnq_g, o_lnq_b, o_Wq, o_bq, q2h, nullptr, 0);

    // ---- phase 3: all four K/V GEMMs, XCD-swizzled. Overwrites cat/cat2. ----
    kv_fused_kernel<<<1056, blk, 0, stream>>>(
        lnbb, lnbb2, sWkb, sWvb, oWkb, oWvb,
        s_bk, s_bv, o_bk, o_bv, kh, vh, kh2, vh2);

    // ---- phase 4: state-branch attention + slot update ----
    attn_part_kernel<4><<<256, blk, 0, stream>>>(qh_s, kh, vh, pmb, plb, paccb);
    attn_comb_kernel<4><<<64, blk, 0, stream>>>(pmb, plb, paccb, attn_s);
    small_gemm_kernel<16><<<256, blk, 0, stream>>>(attn_s, s_Wo, s_bo, lat1, state0, 0);
    small_ln_gemm_kernel<16><<<256, blk, 0, stream>>>(lat1, 0, 1,
        s_lnffn_g, s_lnffn_b, s_fc1_W, s_fc1_b, g1, nullptr, 1);
    small_gemm_kernel<16><<<256, blk, 0, stream>>>(g1, s_fc2_W, s_fc2_b, lat2, lat1, 0);
    gate_fused_kernel<<<NB, blk, 0, stream>>>(lat2, s_lnslot_g, s_lnslot_b,
        slot_ctx, state0, stateNew, out);

    // ---- phase 5: complete out-branch K/V with the 16 new-state rows ----
    small_ln_gemm_kernel<16><<<256, blk, 0, stream>>>(stateNew, 0, 1,
        o_lnkv_g, o_lnkv_b, o_Wk, o_bk, nullptr, kh2, 0);
    small_ln_gemm_kernel<16><<<256, blk, 0, stream>>>(stateNew, 0, 1,
        o_lnkv_g, o_lnkv_b, o_Wv, o_bv, nullptr, vh2, 0);

    // ---- phase 6: out-branch attention (last token) + head ----
    attn_part_kernel<1><<<256, blk, 0, stream>>>(q2h, kh2, vh2, pmb, plb, paccb);
    attn_comb_kernel<1><<<64, blk, 0, stream>>>(pmb, plb, paccb, attn2);
    small_gemm_kernel<4><<<256, blk, 0, stream>>>(attn2, o_Wo, o_bo, lo1, lo_last, 0);
    small_ln_gemm_kernel<4><<<256, blk, 0, stream>>>(lo1, 0, 1,
        o_lnffn_g, o_lnffn_b, o_fc1_W, o_fc1_b, g2, nullptr, 1);
    small_gemm_kernel<4><<<256, blk, 0, stream>>>(g2, o_fc2_W, o_fc2_b, lo2, lo1, 0);
    small_gemm_kernel<4><<<256, blk, 0, stream>>>(lo2, op_W, op_b, out, nullptr, 0);
}